// Round 8
// baseline (48810.059 us; speedup 1.0000x reference)
//
#include <hip/hip_runtime.h>
#include <stdint.h>

#define Ic 128   // input size
#define Hc 256   // hidden size

typedef uint32_t u32;
typedef uint32_t u32x4 __attribute__((ext_vector_type(4)));
using half2v = __attribute__((ext_vector_type(2))) _Float16;

__device__ __forceinline__ u32 pk_rne(float a, float b) {
    _Float16 lo = (_Float16)a, hi = (_Float16)b;
    return (u32)__builtin_bit_cast(uint16_t, lo) |
           ((u32)__builtin_bit_cast(uint16_t, hi) << 16);
}
__device__ __forceinline__ float dot2acc(u32 a, u32 b, float c) {
    return __builtin_amdgcn_fdot2(__builtin_bit_cast(half2v, a),
                                  __builtin_bit_cast(half2v, b), c, false);
}
__device__ __forceinline__ u32 rl(u32 v, int k) {
    return (u32)__builtin_amdgcn_readlane((int)v, k);
}
__device__ __forceinline__ float sigm(float x) {
    return __builtin_amdgcn_rcpf(1.f + __expf(-x));
}
__device__ __forceinline__ float tanh_f(float x) {
    float e = __expf(-2.f * __builtin_fabsf(x));
    float t = (1.f - e) * __builtin_amdgcn_rcpf(1.f + e);
    return __builtin_copysignf(t, x);
}

// ---- 16-B tag-sandwich exchange: {tag, h_even, h_odd, tag} ----
// Producer: write-through store (sc0 sc1) -> updates shared same-XCD L2 + MALL.
// Consumer: sc0 load (L1-bypass, L2-coherent with pair-mate on same XCD).
// Tag rides in the same 16-B transaction as payload: no fences needed; an
// 8-B-torn read makes tags mismatch -> retry. Every 8th retry goes to MALL
// (sc0 sc1) so a wrong XCD-pairing assumption degrades speed, not correctness.
__device__ __forceinline__ void st16_wt(u32x4* p, u32x4 v) {
    asm volatile("global_store_dwordx4 %0, %1, off sc0 sc1" :: "v"(p), "v"(v) : "memory");
}
__device__ __forceinline__ u32x4 ld16_l2(const u32x4* p) {
    u32x4 r;
    asm volatile("global_load_dwordx4 %0, %1, off sc0\n\ts_waitcnt vmcnt(0)"
                 : "=v"(r) : "v"(p) : "memory");
    return r;
}
__device__ __forceinline__ u32x4 ld16_mall(const u32x4* p) {
    u32x4 r;
    asm volatile("global_load_dwordx4 %0, %1, off sc0 sc1\n\ts_waitcnt vmcnt(0)"
                 : "=v"(r) : "v"(p) : "memory");
    return r;
}

// ===================== Encoder =====================
// 256 blocks: pair p = (dir,batch); half k owns hidden units [k*128, k*128+128),
// all 4 gates. Weights register/AGPR-resident. Per-step h-half exchange via
// 32 16-B tagged slots, parity double-buffered. x prefetch depth 2.
__global__ __launch_bounds__(512, 2) void enc_kernel(
    const float* __restrict__ x,
    const float* __restrict__ WihF, const float* __restrict__ WhhF,
    const float* __restrict__ bihF, const float* __restrict__ bhhF,
    const float* __restrict__ WihB, const float* __restrict__ WhhB,
    const float* __restrict__ bihB, const float* __restrict__ bhhB,
    float* __restrict__ hF, float* __restrict__ hB,
    u32x4* __restrict__ xch,    // [128 pairs][2 halves][2 parity][32]
    int T)
{
    const int t    = threadIdx.x;
    const int lane = t & 63;
    const int g    = blockIdx.x;
    const int half = (g >> 3) & 1;               // pair-mates g and g^8: same XCD
    const int p    = ((g >> 4) << 3) | (g & 7);  // pair id 0..127
    const int rev  = p >> 6;
    const int b    = p & 63;

    const int gate = t >> 7;
    const int ul   = t & 127;
    const int r    = gate * Hc + half * 128 + ul;   // global gate row

    const float* Wih = rev ? WihB : WihF;
    const float* Whh = rev ? WhhB : WhhF;
    const float* bih = rev ? bihB : bihF;
    const float* bhh = rev ? bhhB : bhhF;

    __shared__ u32   s_z[256];   // [0:128) h pairs, [128:256) x parity 2x64
    __shared__ float s_g[512];   // local gate rows

    u32 whh[128];   // [0:64) own-half h cols, [64:128) peer-half
    u32 wih[64];
    {
        const float* wr = Whh + (size_t)r * Hc;
        const int ob = half * 64, pb2 = (half ^ 1) * 64;
#pragma unroll
        for (int j = 0; j < 64; j++) whh[j]      = pk_rne(wr[2*(ob+j)],  wr[2*(ob+j)+1]);
#pragma unroll
        for (int j = 0; j < 64; j++) whh[64+j]   = pk_rne(wr[2*(pb2+j)], wr[2*(pb2+j)+1]);
        const float* ir = Wih + (size_t)r * Ic;
#pragma unroll
        for (int j = 0; j < 64; j++) wih[j] = pk_rne(ir[2*j], ir[2*j+1]);
    }
    const float bias = bih[r] + bhh[r];

    const int own_off  = half * 64;
    const int peer_off = (half ^ 1) * 64;
    u32x4* xch_self = xch + ((size_t)(p * 2 + half)) * 64;        // 2 parity x 32
    u32x4* xch_peer = xch + ((size_t)(p * 2 + (half ^ 1))) * 64;

    if (t < 128) s_z[t] = 0u;     // h0 = 0
    if (t >= 128 && t < 192) {    // x for step 0 -> slot 0
        int m = t - 128;
        int ts0 = rev ? (T - 1) : 0;
        const float* xp = x + ((size_t)b * T + ts0) * Ic + 2 * m;
        s_z[128 + m] = pk_rne(xp[0], xp[1]);
    }
    if (t >= 192 && t < 256) {    // x for step 1 -> slot 1
        int m = t - 192;
        int ts1 = rev ? (T - 2) : 1;
        const float* xp = x + ((size_t)b * T + ts1) * Ic + 2 * m;
        s_z[192 + m] = pk_rne(xp[0], xp[1]);
    }
    __syncthreads();

    float c0 = 0.f, c1 = 0.f;   // t<64: cell pairs for own units (2t, 2t+1)
    for (int s = 0; s < T; s++) {
        const bool poller = (s > 0) && ((t >> 6) == 4) && (lane < 32);
        const u32x4* pslot = xch_peer + (s & 1) * 32 + lane;
        u32x4 pv;
        if (poller)   // issue poll load early; latency hides under phase-1 dots
            asm volatile("global_load_dwordx4 %0, %1, off sc0" : "=v"(pv) : "v"(pslot) : "memory");

        // ---- phase 1: x-dots + own-h dots ----
        u32 vzx = s_z[128 + (s & 1) * 64 + lane];
        u32 vzo = s_z[own_off + lane];
        float a0 = bias, a1 = 0.f, a2 = 0.f, a3 = 0.f;
#pragma unroll
        for (int k = 0; k < 64; k += 4) {
            a0 = dot2acc(rl(vzx, k+0), wih[k+0], a0);
            a1 = dot2acc(rl(vzx, k+1), wih[k+1], a1);
            a2 = dot2acc(rl(vzx, k+2), wih[k+2], a2);
            a3 = dot2acc(rl(vzx, k+3), wih[k+3], a3);
        }
#pragma unroll
        for (int k = 0; k < 64; k += 4) {
            a0 = dot2acc(rl(vzo, k+0), whh[k+0], a0);
            a1 = dot2acc(rl(vzo, k+1), whh[k+1], a1);
            a2 = dot2acc(rl(vzo, k+2), whh[k+2], a2);
            a3 = dot2acc(rl(vzo, k+3), whh[k+3], a3);
        }
        if (poller) {
            asm volatile("s_waitcnt vmcnt(0)" ::: "memory");
            asm volatile("" : "+v"(pv));              // pin uses after the wait
            __builtin_amdgcn_sched_barrier(0);
            const u32 tg = (u32)s;
            int it = 0;
            while (!(pv[0] == tg && pv[3] == tg)) {
                __builtin_amdgcn_s_sleep(1);
                pv = ((++it) & 7) ? ld16_l2(pslot) : ld16_mall(pslot);
            }
            s_z[peer_off + 2*lane]     = pv[1];
            s_z[peer_off + 2*lane + 1] = pv[2];
        }
        __syncthreads();

        // ---- phase 2: peer-h dots ----
        u32 vzp = s_z[peer_off + lane];
#pragma unroll
        for (int k = 0; k < 64; k += 4) {
            a0 = dot2acc(rl(vzp, k+0), whh[64+k+0], a0);
            a1 = dot2acc(rl(vzp, k+1), whh[64+k+1], a1);
            a2 = dot2acc(rl(vzp, k+2), whh[64+k+2], a2);
            a3 = dot2acc(rl(vzp, k+3), whh[64+k+3], a3);
        }
        s_g[t] = (a0 + a1) + (a2 + a3);
        __syncthreads();

        const int notlast = (s + 1 < T);
        if (t < 64) {   // cell update + publish (wave 0, all 64 lanes active)
            float i0 = s_g[2*t],     i1 = s_g[2*t+1];
            float f0 = s_g[128+2*t], f1 = s_g[128+2*t+1];
            float g0 = s_g[256+2*t], g1 = s_g[256+2*t+1];
            float o0 = s_g[384+2*t], o1 = s_g[384+2*t+1];
            c0 = sigm(f0)*c0 + sigm(i0)*tanh_f(g0);
            c1 = sigm(f1)*c1 + sigm(i1)*tanh_f(g1);
            float h0 = sigm(o0)*tanh_f(c0);
            float h1 = sigm(o1)*tanh_f(c1);
            u32 hp = pk_rne(h0, h1);
            s_z[own_off + t] = hp;
            u32 he  = (u32)__shfl((int)hp, 2*lane);       // pair 2l
            u32 ho2 = (u32)__shfl((int)hp, 2*lane + 1);   // pair 2l+1
            if (notlast) {
                if (lane < 32) {
                    u32x4 pkt;
                    pkt[0] = (u32)(s + 1); pkt[1] = he; pkt[2] = ho2; pkt[3] = (u32)(s + 1);
                    st16_wt(xch_self + ((s + 1) & 1) * 32 + lane, pkt);
                }
            } else {
                float* ho = (rev ? hB : hF) + (size_t)b * Hc + half * 128 + 2 * t;
                ho[0] = h0; ho[1] = h1;
            }
        } else if (t < 128) {   // x prefetch depth 2 (wave 1)
            int sn = s + 2;
            if (sn < T) {
                int m = t - 64;
                int ts = rev ? (T - 1 - sn) : sn;
                const float* xp = x + ((size_t)b * T + ts) * Ic + 2 * m;
                s_z[128 + (sn & 1) * 64 + m] = pk_rne(xp[0], xp[1]);
            }
        }
        __syncthreads();
    }
}

// ===================== Latent bottleneck =====================
__global__ void lat_kernel(const float* __restrict__ hF, const float* __restrict__ hB,
                           const float* __restrict__ latW, const float* __restrict__ latb,
                           const float* __restrict__ l2hW, const float* __restrict__ l2hb,
                           float* __restrict__ hidden)
{
    int b = blockIdx.x, t = threadIdx.x;  // 256 threads
    __shared__ float s_hn[512];
    __shared__ float s_lat[64];
    s_hn[t]       = hF[(size_t)b * Hc + t];
    s_hn[256 + t] = hB[(size_t)b * Hc + t];
    __syncthreads();
    if (t < 64) {
        float a = latb[t];
        const float* wp = latW + (size_t)t * 512;
        for (int k = 0; k < 512; k++) a += wp[k] * s_hn[k];
        s_lat[t] = a;
    }
    __syncthreads();
    float a = l2hb[t];
    const float* wp = l2hW + (size_t)t * 64;
#pragma unroll
    for (int k = 0; k < 64; k++) a += wp[k] * s_lat[k];
    hidden[(size_t)b * Hc + t] = a;
}

// ===================== Decoder =====================
// 128 blocks = 64 batches x 2 halves. Hidden-split recurrence as encoder.
// Wave roles: 0 = cell+publish; 1 = x prefetch; 1-4 = projection (phase 2);
// 4 (lanes<32) = poll; 5 = out reduce/store. Each half stores its own 64 rows.
__global__ __launch_bounds__(512, 2) void dec_kernel(
    const float* __restrict__ x,
    const float* __restrict__ Wih, const float* __restrict__ Whh,
    const float* __restrict__ bih, const float* __restrict__ bhh,
    const float* __restrict__ outW, const float* __restrict__ outb,
    const float* __restrict__ hidden, float* __restrict__ out,
    u32x4* __restrict__ xch,    // [64 batches][2 halves][2 parity][32]
    int T)
{
    const int t    = threadIdx.x;
    const int lane = t & 63;
    const int g    = blockIdx.x;
    const int half = (g >> 3) & 1;
    const int b    = ((g >> 4) << 3) | (g & 7);   // 0..63
    const int Ts   = T - 1;

    const int gate = t >> 7;
    const int ul   = t & 127;
    const int r    = gate * Hc + half * 128 + ul;

    __shared__ u32   s_z[256];
    __shared__ float s_g[512];
    __shared__ float s_op[256];
    __shared__ u32   s_ow[32 * 256];   // own 64 outW rows packed, keyed by pw

    u32 whh[128], wih[64];
    {
        const float* wr = Whh + (size_t)r * Hc;
        const int ob = half * 64, pb2 = (half ^ 1) * 64;
#pragma unroll
        for (int j = 0; j < 64; j++) whh[j]    = pk_rne(wr[2*(ob+j)],  wr[2*(ob+j)+1]);
#pragma unroll
        for (int j = 0; j < 64; j++) whh[64+j] = pk_rne(wr[2*(pb2+j)], wr[2*(pb2+j)+1]);
        const float* ir = Wih + (size_t)r * Ic;
#pragma unroll
        for (int j = 0; j < 64; j++) wih[j] = pk_rne(ir[2*j], ir[2*j+1]);
    }
    const float bias = bih[r] + bhh[r];

    // projection threads: pw = t-64 in [0,256); row = half*64 + (pw&63), chunk = pw>>6
    if (t >= 64 && t < 320) {
        const int pw = t - 64;
        const float* op = outW + (size_t)(half * 64 + (pw & 63)) * Hc + (size_t)(pw >> 6) * 64;
#pragma unroll
        for (int j = 0; j < 32; j++)
            s_ow[j * 256 + pw] = pk_rne(op[2*j], op[2*j+1]);
    }
    const float outb_r = (t >= 320 && t < 384) ? outb[half * 64 + (t - 320)] : 0.f;

    const int own_off  = half * 64;
    const int peer_off = (half ^ 1) * 64;
    u32x4* xch_self = xch + ((size_t)(b * 2 + half)) * 64;
    u32x4* xch_peer = xch + ((size_t)(b * 2 + (half ^ 1))) * 64;

    if (t < 128) {   // h0 = hidden[b]
        const float* hp = hidden + (size_t)b * Hc + 2 * t;
        s_z[t] = pk_rne(hp[0], hp[1]);
    }
    if (t >= 128 && t < 192) {   // x step 0 -> slot 0
        int m = t - 128;
        const float* xp = x + ((size_t)b * T) * Ic + 2 * m;
        s_z[128 + m] = pk_rne(xp[0], xp[1]);
    }
    if (t >= 192 && t < 256) {   // x step 1 -> slot 1
        int m = t - 192;
        const float* xp = x + ((size_t)b * T + 1) * Ic + 2 * m;
        s_z[192 + m] = pk_rne(xp[0], xp[1]);
    }
    __syncthreads();

    float c0 = 0.f, c1 = 0.f;
    for (int s = 0; s < Ts; s++) {
        const bool poller = (s > 0) && ((t >> 6) == 4) && (lane < 32);
        const u32x4* pslot = xch_peer + (s & 1) * 32 + lane;
        u32x4 pv;
        if (poller)
            asm volatile("global_load_dwordx4 %0, %1, off sc0" : "=v"(pv) : "v"(pslot) : "memory");

        u32 vzx = s_z[128 + (s & 1) * 64 + lane];
        u32 vzo = s_z[own_off + lane];
        float a0 = bias, a1 = 0.f, a2 = 0.f, a3 = 0.f;
#pragma unroll
        for (int k = 0; k < 64; k += 4) {
            a0 = dot2acc(rl(vzx, k+0), wih[k+0], a0);
            a1 = dot2acc(rl(vzx, k+1), wih[k+1], a1);
            a2 = dot2acc(rl(vzx, k+2), wih[k+2], a2);
            a3 = dot2acc(rl(vzx, k+3), wih[k+3], a3);
        }
#pragma unroll
        for (int k = 0; k < 64; k += 4) {
            a0 = dot2acc(rl(vzo, k+0), whh[k+0], a0);
            a1 = dot2acc(rl(vzo, k+1), whh[k+1], a1);
            a2 = dot2acc(rl(vzo, k+2), whh[k+2], a2);
            a3 = dot2acc(rl(vzo, k+3), whh[k+3], a3);
        }
        if (poller) {
            asm volatile("s_waitcnt vmcnt(0)" ::: "memory");
            asm volatile("" : "+v"(pv));
            __builtin_amdgcn_sched_barrier(0);
            const u32 tg = (u32)s;
            int it = 0;
            while (!(pv[0] == tg && pv[3] == tg)) {
                __builtin_amdgcn_s_sleep(1);
                pv = ((++it) & 7) ? ld16_l2(pslot) : ld16_mall(pslot);
            }
            s_z[peer_off + 2*lane]     = pv[1];
            s_z[peer_off + 2*lane + 1] = pv[2];
        }
        __syncthreads();

        u32 vzp = s_z[peer_off + lane];
#pragma unroll
        for (int k = 0; k < 64; k += 4) {
            a0 = dot2acc(rl(vzp, k+0), whh[64+k+0], a0);
            a1 = dot2acc(rl(vzp, k+1), whh[64+k+1], a1);
            a2 = dot2acc(rl(vzp, k+2), whh[64+k+2], a2);
            a3 = dot2acc(rl(vzp, k+3), whh[64+k+3], a3);
        }
        s_g[t] = (a0 + a1) + (a2 + a3);

        if (s > 0 && t >= 64 && t < 320) {   // projection of h_s -> decoded[s-1]
            const int pw   = t - 64;
            const int kslw = pw >> 6;           // wave-uniform 0..3
            const int kb   = (kslw & 1) * 32;
            u32 vplo = s_z[lane];               // h pairs 0..63
            u32 vphi = s_z[64 + lane];          // h pairs 64..127
            float p0 = 0.f, p1 = 0.f;
#pragma unroll
            for (int j = 0; j < 32; j += 2) {
                u32 h0b = (kslw < 2) ? rl(vplo, kb + j)     : rl(vphi, kb + j);
                u32 h1b = (kslw < 2) ? rl(vplo, kb + j + 1) : rl(vphi, kb + j + 1);
                p0 = dot2acc(h0b, s_ow[(j)     * 256 + pw], p0);
                p1 = dot2acc(h1b, s_ow[(j + 1) * 256 + pw], p1);
            }
            s_op[(pw & 63) * 4 + kslw] = p0 + p1;
        }
        __syncthreads();

        if (t < 64) {   // cell + publish (every step; peer tail needs h_Ts)
            float i0 = s_g[2*t],     i1 = s_g[2*t+1];
            float f0 = s_g[128+2*t], f1 = s_g[128+2*t+1];
            float g0 = s_g[256+2*t], g1 = s_g[256+2*t+1];
            float o0 = s_g[384+2*t], o1 = s_g[384+2*t+1];
            c0 = sigm(f0)*c0 + sigm(i0)*tanh_f(g0);
            c1 = sigm(f1)*c1 + sigm(i1)*tanh_f(g1);
            float h0 = sigm(o0)*tanh_f(c0);
            float h1 = sigm(o1)*tanh_f(c1);
            u32 hp = pk_rne(h0, h1);
            s_z[own_off + t] = hp;
            u32 he  = (u32)__shfl((int)hp, 2*lane);
            u32 ho2 = (u32)__shfl((int)hp, 2*lane + 1);
            if (lane < 32) {
                u32x4 pkt;
                pkt[0] = (u32)(s + 1); pkt[1] = he; pkt[2] = ho2; pkt[3] = (u32)(s + 1);
                st16_wt(xch_self + ((s + 1) & 1) * 32 + lane, pkt);
            }
        } else if (t < 128) {   // x prefetch depth 2
            int sn = s + 2;
            if (sn < Ts) {
                int m = t - 64;
                const float* xp = x + ((size_t)b * T + sn) * Ic + 2 * m;
                s_z[128 + (sn & 1) * 64 + m] = pk_rne(xp[0], xp[1]);
            }
        } else if (t >= 320 && t < 384 && s > 0) {   // reduce + store own 64 rows
            int rr = t - 320;
            float y = outb_r + ((s_op[rr*4+0] + s_op[rr*4+1]) + (s_op[rr*4+2] + s_op[rr*4+3]));
            out[((size_t)b * Ts + (s - 1)) * Ic + half * 64 + rr] = y;
        }
        __syncthreads();
    }

    // tail: decoded[b, Ts-1] from h_Ts
    if (((t >> 6) == 4) && (lane < 32)) {
        const u32x4* pslot = xch_peer + (Ts & 1) * 32 + lane;
        const u32 tg = (u32)Ts;
        u32x4 pv = ld16_l2(pslot);
        int it = 0;
        while (!(pv[0] == tg && pv[3] == tg)) {
            __builtin_amdgcn_s_sleep(1);
            pv = ((++it) & 7) ? ld16_l2(pslot) : ld16_mall(pslot);
        }
        s_z[peer_off + 2*lane]     = pv[1];
        s_z[peer_off + 2*lane + 1] = pv[2];
    }
    __syncthreads();
    if (t >= 64 && t < 320) {
        const int pw   = t - 64;
        const int kslw = pw >> 6;
        const int kb   = (kslw & 1) * 32;
        u32 vplo = s_z[lane];
        u32 vphi = s_z[64 + lane];
        float p0 = 0.f, p1 = 0.f;
#pragma unroll
        for (int j = 0; j < 32; j += 2) {
            u32 h0b = (kslw < 2) ? rl(vplo, kb + j)     : rl(vphi, kb + j);
            u32 h1b = (kslw < 2) ? rl(vplo, kb + j + 1) : rl(vphi, kb + j + 1);
            p0 = dot2acc(h0b, s_ow[(j)     * 256 + pw], p0);
            p1 = dot2acc(h1b, s_ow[(j + 1) * 256 + pw], p1);
        }
        s_op[(pw & 63) * 4 + kslw] = p0 + p1;
    }
    __syncthreads();
    if (t >= 320 && t < 384) {
        int rr = t - 320;
        float y = outb_r + ((s_op[rr*4+0] + s_op[rr*4+1]) + (s_op[rr*4+2] + s_op[rr*4+3]));
        out[((size_t)b * Ts + (Ts - 1)) * Ic + half * 64 + rr] = y;
    }
}

extern "C" void kernel_launch(void* const* d_in, const int* in_sizes, int n_in,
                              void* d_out, int out_size, void* d_ws, size_t ws_size,
                              hipStream_t stream)
{
    const float* x    = (const float*)d_in[0];
    const float* WihF = (const float*)d_in[1];
    const float* WhhF = (const float*)d_in[2];
    const float* bihF = (const float*)d_in[3];
    const float* bhhF = (const float*)d_in[4];
    const float* WihB = (const float*)d_in[5];
    const float* WhhB = (const float*)d_in[6];
    const float* bihB = (const float*)d_in[7];
    const float* bhhB = (const float*)d_in[8];
    const float* latW = (const float*)d_in[9];
    const float* latb = (const float*)d_in[10];
    const float* l2hW = (const float*)d_in[11];
    const float* l2hb = (const float*)d_in[12];
    const float* dWih = (const float*)d_in[13];
    const float* dWhh = (const float*)d_in[14];
    const float* dbih = (const float*)d_in[15];
    const float* dbhh = (const float*)d_in[16];
    const float* outW = (const float*)d_in[17];
    const float* outb = (const float*)d_in[18];

    const int T = in_sizes[0] / (64 * Ic);  // 4096

    float* ws  = (float*)d_ws;
    float* hFp = ws;                 // [64,256]
    float* hBp = ws + 16384;         // [64,256]
    float* hid = ws + 32768;         // [64,256]
    u32x4* encXch = (u32x4*)(ws + 49152);   // 128*2*2*32 = 16384 slots (256 KB)
    u32x4* decXch = encXch + 16384;         // 64*2*2*32  = 8192 slots (128 KB)

    // zero all tags (graph replay must restart deterministically)
    hipMemsetAsync(encXch, 0, (16384 + 8192) * sizeof(u32x4), stream);

    enc_kernel<<<256, 512, 0, stream>>>(x, WihF, WhhF, bihF, bhhF,
                                        WihB, WhhB, bihB, bhhB,
                                        hFp, hBp, encXch, T);
    lat_kernel<<<64, 256, 0, stream>>>(hFp, hBp, latW, latb, l2hW, l2hb, hid);
    dec_kernel<<<128, 512, 0, stream>>>(x, dWih, dWhh, dbih, dbhh,
                                        outW, outb, hid, (float*)d_out,
                                        decXch, T);
}

// Round 9
// 33614.160 us; speedup vs baseline: 1.4521x; 1.4521x over previous
//
#include <hip/hip_runtime.h>
#include <stdint.h>

#define Ic 128   // input size
#define Hc 256   // hidden size

typedef uint32_t u32;
typedef unsigned long long u64;
using half2v = __attribute__((ext_vector_type(2))) _Float16;

__device__ __forceinline__ u32 pk_rne(float a, float b) {
    _Float16 lo = (_Float16)a, hi = (_Float16)b;
    return (u32)__builtin_bit_cast(uint16_t, lo) |
           ((u32)__builtin_bit_cast(uint16_t, hi) << 16);
}
__device__ __forceinline__ float dot2acc(u32 a, u32 b, float c) {
    return __builtin_amdgcn_fdot2(__builtin_bit_cast(half2v, a),
                                  __builtin_bit_cast(half2v, b), c, false);
}
__device__ __forceinline__ u32 rl(u32 v, int k) {
    return (u32)__builtin_amdgcn_readlane((int)v, k);
}
__device__ __forceinline__ float sigm(float x) {
    return __builtin_amdgcn_rcpf(1.f + __expf(-x));
}
__device__ __forceinline__ float tanh_f(float x) {
    float e = __expf(-2.f * __builtin_fabsf(x));
    float t = (1.f - e) * __builtin_amdgcn_rcpf(1.f + e);
    return __builtin_copysignf(t, x);
}
// Tagged-slot exchange (round-7 proven): (tag<<32)|payload in ONE u64, relaxed
// agent atomics. Per-location coherence orders tag with data — no fences, no
// cache maintenance. Parity double-buffer prevents producer overrun.
__device__ __forceinline__ u64 aload64(const u64* p) {
    return __hip_atomic_load(p, __ATOMIC_RELAXED, __HIP_MEMORY_SCOPE_AGENT);
}
__device__ __forceinline__ void astore64(u64* p, u64 v) {
    __hip_atomic_store(p, v, __ATOMIC_RELAXED, __HIP_MEMORY_SCOPE_AGENT);
}

// ===================== Encoder =====================
// 256 blocks of 256 threads (4 waves = 1 wave/SIMD -> full 512-reg budget).
// Pair p = (dir,batch); half k owns hidden units [k*128,k*128+128), all 4 gates
// = 512 rows. Thread t owns TWO rows: lr=t (gates 0/1) and lr=t+256 (gates 2/3),
// unit = t&127. Weights fully register-resident (384 u32/thread); the two rows
// share every readlane broadcast. Roles after B2: wave0 cell+publish,
// wave1 x-prefetch(depth2), wave3 polls peer h.
__global__ __launch_bounds__(256, 1) void enc_kernel(
    const float* __restrict__ x,
    const float* __restrict__ WihF, const float* __restrict__ WhhF,
    const float* __restrict__ bihF, const float* __restrict__ bhhF,
    const float* __restrict__ WihB, const float* __restrict__ WhhB,
    const float* __restrict__ bihB, const float* __restrict__ bhhB,
    float* __restrict__ hF, float* __restrict__ hB,
    u64* __restrict__ xch,    // [128 pairs][2 halves][2 parity][64]
    int T)
{
    const int t    = threadIdx.x;
    const int lane = t & 63;
    const int g    = blockIdx.x;
    const int half = (g >> 3) & 1;               // pair-mates g and g^8
    const int p    = ((g >> 4) << 3) | (g & 7);  // pair id 0..127
    const int rev  = p >> 6;
    const int b    = p & 63;

    const int ug = t & 127;                       // unit-local
    const int rA = (t >> 7) * Hc + half * 128 + ug;        // gate 0/1 row
    const int rB = ((t >> 7) + 2) * Hc + half * 128 + ug;  // gate 2/3 row

    const float* Wih = rev ? WihB : WihF;
    const float* Whh = rev ? WhhB : WhhF;
    const float* bih = rev ? bihB : bihF;
    const float* bhh = rev ? bhhB : bhhF;

    __shared__ u32   s_z[256];   // [0:128) h pairs (global unit order), [128:256) x parity
    __shared__ float s_g[512];   // local gate rows: s_g[gate*128+unit] via s_g[t], s_g[t+256]

    u32 whAo[64], whAp[64], wiA[64];   // row A: own-h, peer-h, x
    u32 whBo[64], whBp[64], wiB[64];   // row B
    {
        const int ob = half * 64, pb2 = (half ^ 1) * 64;
        const float* wrA = Whh + (size_t)rA * Hc;
        const float* wrB = Whh + (size_t)rB * Hc;
#pragma unroll
        for (int j = 0; j < 64; j++) {
            whAo[j] = pk_rne(wrA[2*(ob+j)],  wrA[2*(ob+j)+1]);
            whBo[j] = pk_rne(wrB[2*(ob+j)],  wrB[2*(ob+j)+1]);
            whAp[j] = pk_rne(wrA[2*(pb2+j)], wrA[2*(pb2+j)+1]);
            whBp[j] = pk_rne(wrB[2*(pb2+j)], wrB[2*(pb2+j)+1]);
        }
        const float* irA = Wih + (size_t)rA * Ic;
        const float* irB = Wih + (size_t)rB * Ic;
#pragma unroll
        for (int j = 0; j < 64; j++) {
            wiA[j] = pk_rne(irA[2*j], irA[2*j+1]);
            wiB[j] = pk_rne(irB[2*j], irB[2*j+1]);
        }
    }
    const float biasA = bih[rA] + bhh[rA];
    const float biasB = bih[rB] + bhh[rB];

    const int own_off  = half * 64;
    const int peer_off = (half ^ 1) * 64;
    u64* xch_self = xch + ((size_t)(p * 2 + half)) * 128;        // 2 parity x 64
    u64* xch_peer = xch + ((size_t)(p * 2 + (half ^ 1))) * 128;

    if (t < 128) s_z[t] = 0u;     // h0 = 0
    if (t >= 128 && t < 192) {    // x step 0 -> parity slot 0
        int m = t - 128;
        int ts0 = rev ? (T - 1) : 0;
        const float* xp = x + ((size_t)b * T + ts0) * Ic + 2 * m;
        s_z[128 + m] = pk_rne(xp[0], xp[1]);
    }
    if (t >= 192 && t < 256) {    // x step 1 -> parity slot 1
        int m = t - 192;
        int ts1 = rev ? (T - 2) : 1;
        const float* xp = x + ((size_t)b * T + ts1) * Ic + 2 * m;
        s_z[192 + m] = pk_rne(xp[0], xp[1]);
    }
    __syncthreads();

    float c0 = 0.f, c1 = 0.f;   // t<64: cells for units 2t, 2t+1
    for (int s = 0; s < T; s++) {
        // ---- phase 1: x-dots + own-h dots (broadcasts shared by rows A,B) ----
        u32 vzx = s_z[128 + (s & 1) * 64 + lane];
        u32 vzo = s_z[own_off + lane];
        float aA0 = biasA, aA1 = 0.f, aA2 = 0.f, aA3 = 0.f;
        float aB0 = biasB, aB1 = 0.f, aB2 = 0.f, aB3 = 0.f;
#pragma unroll
        for (int k = 0; k < 64; k += 4) {
            u32 h0 = rl(vzx, k+0), h1 = rl(vzx, k+1), h2 = rl(vzx, k+2), h3 = rl(vzx, k+3);
            aA0 = dot2acc(h0, wiA[k+0], aA0); aB0 = dot2acc(h0, wiB[k+0], aB0);
            aA1 = dot2acc(h1, wiA[k+1], aA1); aB1 = dot2acc(h1, wiB[k+1], aB1);
            aA2 = dot2acc(h2, wiA[k+2], aA2); aB2 = dot2acc(h2, wiB[k+2], aB2);
            aA3 = dot2acc(h3, wiA[k+3], aA3); aB3 = dot2acc(h3, wiB[k+3], aB3);
        }
#pragma unroll
        for (int k = 0; k < 64; k += 4) {
            u32 h0 = rl(vzo, k+0), h1 = rl(vzo, k+1), h2 = rl(vzo, k+2), h3 = rl(vzo, k+3);
            aA0 = dot2acc(h0, whAo[k+0], aA0); aB0 = dot2acc(h0, whBo[k+0], aB0);
            aA1 = dot2acc(h1, whAo[k+1], aA1); aB1 = dot2acc(h1, whBo[k+1], aB1);
            aA2 = dot2acc(h2, whAo[k+2], aA2); aB2 = dot2acc(h2, whBo[k+2], aB2);
            aA3 = dot2acc(h3, whAo[k+3], aA3); aB3 = dot2acc(h3, whBo[k+3], aB3);
        }
        // wave 3: poll tagged peer slots, fill peer h-half
        if (s > 0 && (t >> 6) == 3) {
            u64 v;
            while ((int)((v = aload64(&xch_peer[(s & 1) * 64 + lane])) >> 32) < s)
                __builtin_amdgcn_s_sleep(1);
            s_z[peer_off + lane] = (u32)v;
        }
        __syncthreads();

        // ---- phase 2: peer-h dots ----
        u32 vzp = s_z[peer_off + lane];
#pragma unroll
        for (int k = 0; k < 64; k += 4) {
            u32 h0 = rl(vzp, k+0), h1 = rl(vzp, k+1), h2 = rl(vzp, k+2), h3 = rl(vzp, k+3);
            aA0 = dot2acc(h0, whAp[k+0], aA0); aB0 = dot2acc(h0, whBp[k+0], aB0);
            aA1 = dot2acc(h1, whAp[k+1], aA1); aB1 = dot2acc(h1, whBp[k+1], aB1);
            aA2 = dot2acc(h2, whAp[k+2], aA2); aB2 = dot2acc(h2, whBp[k+2], aB2);
            aA3 = dot2acc(h3, whAp[k+3], aA3); aB3 = dot2acc(h3, whBp[k+3], aB3);
        }
        s_g[t]       = (aA0 + aA1) + (aA2 + aA3);
        s_g[t + 256] = (aB0 + aB1) + (aB2 + aB3);
        __syncthreads();

        const int notlast = (s + 1 < T);
        if (t < 64) {   // cell update for units 2t, 2t+1
            float i0 = s_g[2*t],     i1 = s_g[2*t+1];
            float f0 = s_g[128+2*t], f1 = s_g[128+2*t+1];
            float g0 = s_g[256+2*t], g1 = s_g[256+2*t+1];
            float o0 = s_g[384+2*t], o1 = s_g[384+2*t+1];
            c0 = sigm(f0)*c0 + sigm(i0)*tanh_f(g0);
            c1 = sigm(f1)*c1 + sigm(i1)*tanh_f(g1);
            float h0 = sigm(o0)*tanh_f(c0);
            float h1 = sigm(o1)*tanh_f(c1);
            u32 hp = pk_rne(h0, h1);
            s_z[own_off + t] = hp;
            if (notlast) {
                astore64(&xch_self[((s+1) & 1) * 64 + t],
                         ((u64)(u32)(s + 1) << 32) | (u64)hp);
            } else {
                float* ho = (rev ? hB : hF) + (size_t)b * Hc + half * 128 + 2 * t;
                ho[0] = h0; ho[1] = h1;
            }
        } else if (t < 128) {   // x prefetch depth 2
            int sn = s + 2;
            if (sn < T) {
                int m = t - 64;
                int ts = rev ? (T - 1 - sn) : sn;
                const float* xp = x + ((size_t)b * T + ts) * Ic + 2 * m;
                s_z[128 + (sn & 1) * 64 + m] = pk_rne(xp[0], xp[1]);
            }
        }
        __syncthreads();
    }
}

// ===================== Latent bottleneck =====================
__global__ void lat_kernel(const float* __restrict__ hF, const float* __restrict__ hB,
                           const float* __restrict__ latW, const float* __restrict__ latb,
                           const float* __restrict__ l2hW, const float* __restrict__ l2hb,
                           float* __restrict__ hidden)
{
    int b = blockIdx.x, t = threadIdx.x;  // 256 threads
    __shared__ float s_hn[512];
    __shared__ float s_lat[64];
    s_hn[t]       = hF[(size_t)b * Hc + t];
    s_hn[256 + t] = hB[(size_t)b * Hc + t];
    __syncthreads();
    if (t < 64) {
        float a = latb[t];
        const float* wp = latW + (size_t)t * 512;
        for (int k = 0; k < 512; k++) a += wp[k] * s_hn[k];
        s_lat[t] = a;
    }
    __syncthreads();
    float a = l2hb[t];
    const float* wp = l2hW + (size_t)t * 64;
#pragma unroll
    for (int k = 0; k < 64; k++) a += wp[k] * s_lat[k];
    hidden[(size_t)b * Hc + t] = a;
}

// ===================== Decoder =====================
// 128 blocks of 256 threads. Recurrence as encoder (2 rows/thread).
// Fused projection: every thread projects row half*64+(t&63), h-chunk t>>6
// (wave-uniform) from LDS outW. Each half stores its own 64 out rows.
// Roles after B2: wave0 cell+publish, wave1 x-prefetch, wave2 out reduce/store,
// wave3 polls.
__global__ __launch_bounds__(256, 1) void dec_kernel(
    const float* __restrict__ x,
    const float* __restrict__ Wih, const float* __restrict__ Whh,
    const float* __restrict__ bih, const float* __restrict__ bhh,
    const float* __restrict__ outW, const float* __restrict__ outb,
    const float* __restrict__ hidden, float* __restrict__ out,
    u64* __restrict__ xch,    // [64 batches][2 halves][2 parity][64]
    int T)
{
    const int t    = threadIdx.x;
    const int lane = t & 63;
    const int g    = blockIdx.x;
    const int half = (g >> 3) & 1;
    const int b    = ((g >> 4) << 3) | (g & 7);   // 0..63
    const int Ts   = T - 1;

    const int ug = t & 127;
    const int rA = (t >> 7) * Hc + half * 128 + ug;
    const int rB = ((t >> 7) + 2) * Hc + half * 128 + ug;

    __shared__ u32   s_z[256];
    __shared__ float s_g[512];
    __shared__ float s_op[256];
    __shared__ u32   s_ow[32 * 256];   // own 64 outW rows packed, keyed by t

    u32 whAo[64], whAp[64], wiA[64];
    u32 whBo[64], whBp[64], wiB[64];
    {
        const int ob = half * 64, pb2 = (half ^ 1) * 64;
        const float* wrA = Whh + (size_t)rA * Hc;
        const float* wrB = Whh + (size_t)rB * Hc;
#pragma unroll
        for (int j = 0; j < 64; j++) {
            whAo[j] = pk_rne(wrA[2*(ob+j)],  wrA[2*(ob+j)+1]);
            whBo[j] = pk_rne(wrB[2*(ob+j)],  wrB[2*(ob+j)+1]);
            whAp[j] = pk_rne(wrA[2*(pb2+j)], wrA[2*(pb2+j)+1]);
            whBp[j] = pk_rne(wrB[2*(pb2+j)], wrB[2*(pb2+j)+1]);
        }
        const float* irA = Wih + (size_t)rA * Ic;
        const float* irB = Wih + (size_t)rB * Ic;
#pragma unroll
        for (int j = 0; j < 64; j++) {
            wiA[j] = pk_rne(irA[2*j], irA[2*j+1]);
            wiB[j] = pk_rne(irB[2*j], irB[2*j+1]);
        }
    }
    const float biasA = bih[rA] + bhh[rA];
    const float biasB = bih[rB] + bhh[rB];

    {   // stage own half's 64 outW rows: thread t = row half*64+(t&63), chunk t>>6
        const float* op = outW + (size_t)(half * 64 + (t & 63)) * Hc + (size_t)(t >> 6) * 64;
#pragma unroll
        for (int j = 0; j < 32; j++)
            s_ow[j * 256 + t] = pk_rne(op[2*j], op[2*j+1]);
    }
    const float outb_r = (t >= 128 && t < 192) ? outb[half * 64 + (t - 128)] : 0.f;

    const int own_off  = half * 64;
    const int peer_off = (half ^ 1) * 64;
    u64* xch_self = xch + ((size_t)(b * 2 + half)) * 128;
    u64* xch_peer = xch + ((size_t)(b * 2 + (half ^ 1))) * 128;

    if (t < 128) {   // h0 = hidden[b]
        const float* hp = hidden + (size_t)b * Hc + 2 * t;
        s_z[t] = pk_rne(hp[0], hp[1]);
    }
    if (t >= 128 && t < 192) {   // x step 0 -> slot 0
        int m = t - 128;
        const float* xp = x + ((size_t)b * T) * Ic + 2 * m;
        s_z[128 + m] = pk_rne(xp[0], xp[1]);
    }
    if (t >= 192 && t < 256) {   // x step 1 -> slot 1
        int m = t - 192;
        const float* xp = x + ((size_t)b * T + 1) * Ic + 2 * m;
        s_z[192 + m] = pk_rne(xp[0], xp[1]);
    }
    __syncthreads();

    float c0 = 0.f, c1 = 0.f;
    for (int s = 0; s < Ts; s++) {
        u32 vzx = s_z[128 + (s & 1) * 64 + lane];
        u32 vzo = s_z[own_off + lane];
        float aA0 = biasA, aA1 = 0.f, aA2 = 0.f, aA3 = 0.f;
        float aB0 = biasB, aB1 = 0.f, aB2 = 0.f, aB3 = 0.f;
#pragma unroll
        for (int k = 0; k < 64; k += 4) {
            u32 h0 = rl(vzx, k+0), h1 = rl(vzx, k+1), h2 = rl(vzx, k+2), h3 = rl(vzx, k+3);
            aA0 = dot2acc(h0, wiA[k+0], aA0); aB0 = dot2acc(h0, wiB[k+0], aB0);
            aA1 = dot2acc(h1, wiA[k+1], aA1); aB1 = dot2acc(h1, wiB[k+1], aB1);
            aA2 = dot2acc(h2, wiA[k+2], aA2); aB2 = dot2acc(h2, wiB[k+2], aB2);
            aA3 = dot2acc(h3, wiA[k+3], aA3); aB3 = dot2acc(h3, wiB[k+3], aB3);
        }
#pragma unroll
        for (int k = 0; k < 64; k += 4) {
            u32 h0 = rl(vzo, k+0), h1 = rl(vzo, k+1), h2 = rl(vzo, k+2), h3 = rl(vzo, k+3);
            aA0 = dot2acc(h0, whAo[k+0], aA0); aB0 = dot2acc(h0, whBo[k+0], aB0);
            aA1 = dot2acc(h1, whAo[k+1], aA1); aB1 = dot2acc(h1, whBo[k+1], aB1);
            aA2 = dot2acc(h2, whAo[k+2], aA2); aB2 = dot2acc(h2, whBo[k+2], aB2);
            aA3 = dot2acc(h3, whAo[k+3], aA3); aB3 = dot2acc(h3, whBo[k+3], aB3);
        }
        if (s > 0 && (t >> 6) == 3) {
            u64 v;
            while ((int)((v = aload64(&xch_peer[(s & 1) * 64 + lane])) >> 32) < s)
                __builtin_amdgcn_s_sleep(1);
            s_z[peer_off + lane] = (u32)v;
        }
        __syncthreads();

        u32 vzp = s_z[peer_off + lane];
#pragma unroll
        for (int k = 0; k < 64; k += 4) {
            u32 h0 = rl(vzp, k+0), h1 = rl(vzp, k+1), h2 = rl(vzp, k+2), h3 = rl(vzp, k+3);
            aA0 = dot2acc(h0, whAp[k+0], aA0); aB0 = dot2acc(h0, whBp[k+0], aB0);
            aA1 = dot2acc(h1, whAp[k+1], aA1); aB1 = dot2acc(h1, whBp[k+1], aB1);
            aA2 = dot2acc(h2, whAp[k+2], aA2); aB2 = dot2acc(h2, whBp[k+2], aB2);
            aA3 = dot2acc(h3, whAp[k+3], aA3); aB3 = dot2acc(h3, whBp[k+3], aB3);
        }
        s_g[t]       = (aA0 + aA1) + (aA2 + aA3);
        s_g[t + 256] = (aB0 + aB1) + (aB2 + aB3);

        if (s > 0) {   // projection of h_s -> decoded[s-1] partials (all threads)
            const int ksl = t >> 6;             // wave-uniform 0..3
            const int kb  = (ksl & 1) * 32;
            u32 vplo = s_z[lane];               // h pairs 0..63
            u32 vphi = s_z[64 + lane];          // h pairs 64..127
            float p0 = 0.f, p1 = 0.f;
#pragma unroll
            for (int j = 0; j < 32; j += 2) {
                u32 h0b = (ksl < 2) ? rl(vplo, kb + j)     : rl(vphi, kb + j);
                u32 h1b = (ksl < 2) ? rl(vplo, kb + j + 1) : rl(vphi, kb + j + 1);
                p0 = dot2acc(h0b, s_ow[(j)     * 256 + t], p0);
                p1 = dot2acc(h1b, s_ow[(j + 1) * 256 + t], p1);
            }
            s_op[(t & 63) * 4 + ksl] = p0 + p1;
        }
        __syncthreads();

        if (t < 64) {   // cell + publish (every step; peer tail needs h_Ts)
            float i0 = s_g[2*t],     i1 = s_g[2*t+1];
            float f0 = s_g[128+2*t], f1 = s_g[128+2*t+1];
            float g0 = s_g[256+2*t], g1 = s_g[256+2*t+1];
            float o0 = s_g[384+2*t], o1 = s_g[384+2*t+1];
            c0 = sigm(f0)*c0 + sigm(i0)*tanh_f(g0);
            c1 = sigm(f1)*c1 + sigm(i1)*tanh_f(g1);
            float h0 = sigm(o0)*tanh_f(c0);
            float h1 = sigm(o1)*tanh_f(c1);
            u32 hp = pk_rne(h0, h1);
            s_z[own_off + t] = hp;
            astore64(&xch_self[((s+1) & 1) * 64 + t],
                     ((u64)(u32)(s + 1) << 32) | (u64)hp);
        } else if (t < 128) {   // x prefetch depth 2
            int sn = s + 2;
            if (sn < Ts) {
                int m = t - 64;
                const float* xp = x + ((size_t)b * T + sn) * Ic + 2 * m;
                s_z[128 + (sn & 1) * 64 + m] = pk_rne(xp[0], xp[1]);
            }
        } else if (t < 192 && s > 0) {   // reduce + store own 64 out rows
            int rr = t - 128;
            float y = outb_r + ((s_op[rr*4+0] + s_op[rr*4+1]) + (s_op[rr*4+2] + s_op[rr*4+3]));
            out[((size_t)b * Ts + (s - 1)) * Ic + half * 64 + rr] = y;
        }
        __syncthreads();
    }

    // tail: decoded[b, Ts-1] from h_Ts
    if ((t >> 6) == 3) {
        u64 v;
        while ((int)((v = aload64(&xch_peer[(Ts & 1) * 64 + lane])) >> 32) < Ts)
            __builtin_amdgcn_s_sleep(1);
        s_z[peer_off + lane] = (u32)v;
    }
    __syncthreads();
    {
        const int ksl = t >> 6;
        const int kb  = (ksl & 1) * 32;
        u32 vplo = s_z[lane];
        u32 vphi = s_z[64 + lane];
        float p0 = 0.f, p1 = 0.f;
#pragma unroll
        for (int j = 0; j < 32; j += 2) {
            u32 h0b = (ksl < 2) ? rl(vplo, kb + j)     : rl(vphi, kb + j);
            u32 h1b = (ksl < 2) ? rl(vplo, kb + j + 1) : rl(vphi, kb + j + 1);
            p0 = dot2acc(h0b, s_ow[(j)     * 256 + t], p0);
            p1 = dot2acc(h1b, s_ow[(j + 1) * 256 + t], p1);
        }
        s_op[(t & 63) * 4 + ksl] = p0 + p1;
    }
    __syncthreads();
    if (t >= 128 && t < 192) {
        int rr = t - 128;
        float y = outb_r + ((s_op[rr*4+0] + s_op[rr*4+1]) + (s_op[rr*4+2] + s_op[rr*4+3]));
        out[((size_t)b * Ts + (Ts - 1)) * Ic + half * 64 + rr] = y;
    }
}

extern "C" void kernel_launch(void* const* d_in, const int* in_sizes, int n_in,
                              void* d_out, int out_size, void* d_ws, size_t ws_size,
                              hipStream_t stream)
{
    const float* x    = (const float*)d_in[0];
    const float* WihF = (const float*)d_in[1];
    const float* WhhF = (const float*)d_in[2];
    const float* bihF = (const float*)d_in[3];
    const float* bhhF = (const float*)d_in[4];
    const float* WihB = (const float*)d_in[5];
    const float* WhhB = (const float*)d_in[6];
    const float* bihB = (const float*)d_in[7];
    const float* bhhB = (const float*)d_in[8];
    const float* latW = (const float*)d_in[9];
    const float* latb = (const float*)d_in[10];
    const float* l2hW = (const float*)d_in[11];
    const float* l2hb = (const float*)d_in[12];
    const float* dWih = (const float*)d_in[13];
    const float* dWhh = (const float*)d_in[14];
    const float* dbih = (const float*)d_in[15];
    const float* dbhh = (const float*)d_in[16];
    const float* outW = (const float*)d_in[17];
    const float* outb = (const float*)d_in[18];

    const int T = in_sizes[0] / (64 * Ic);  // 4096

    float* ws  = (float*)d_ws;
    float* hFp = ws;                 // [64,256]
    float* hBp = ws + 16384;         // [64,256]
    float* hid = ws + 32768;         // [64,256]
    u64* encXch = (u64*)(ws + 49152);   // 128*2*2*64 = 32768 u64
    u64* decXch = encXch + 32768;       // 64*2*2*64  = 16384 u64

    // zero all tags (graph replay must restart deterministically)
    hipMemsetAsync(encXch, 0, (32768 + 16384) * sizeof(u64), stream);

    enc_kernel<<<256, 256, 0, stream>>>(x, WihF, WhhF, bihF, bhhF,
                                        WihB, WhhB, bihB, bhhB,
                                        hFp, hBp, encXch, T);
    lat_kernel<<<64, 256, 0, stream>>>(hFp, hBp, latW, latb, l2hW, l2hb, hid);
    dec_kernel<<<128, 256, 0, stream>>>(x, dWih, dWhh, dbih, dbhh,
                                        outW, outb, hid, (float*)d_out,
                                        decXch, T);
}

// Round 10
// 30371.027 us; speedup vs baseline: 1.6071x; 1.1068x over previous
//
#include <hip/hip_runtime.h>
#include <stdint.h>

#define Ic 128   // input size
#define Hc 256   // hidden size

typedef uint32_t u32;
typedef unsigned long long u64;
using half2v = __attribute__((ext_vector_type(2))) _Float16;

__device__ __forceinline__ u32 pk_rne(float a, float b) {
    _Float16 lo = (_Float16)a, hi = (_Float16)b;
    return (u32)__builtin_bit_cast(uint16_t, lo) |
           ((u32)__builtin_bit_cast(uint16_t, hi) << 16);
}
__device__ __forceinline__ float dot2acc(u32 a, u32 b, float c) {
    return __builtin_amdgcn_fdot2(__builtin_bit_cast(half2v, a),
                                  __builtin_bit_cast(half2v, b), c, false);
}
__device__ __forceinline__ u32 rl(u32 v, int k) {
    return (u32)__builtin_amdgcn_readlane((int)v, k);
}
__device__ __forceinline__ float sigm(float x) {
    return __builtin_amdgcn_rcpf(1.f + __expf(-x));
}
__device__ __forceinline__ float tanh_f(float x) {
    float e = __expf(-2.f * __builtin_fabsf(x));
    float t = (1.f - e) * __builtin_amdgcn_rcpf(1.f + e);
    return __builtin_copysignf(t, x);
}
// Tagged-slot exchange (round-7 proven): (tag<<32)|payload in ONE u64, relaxed
// agent atomics. Per-location coherence orders tag with data — no fences.
// Parity double-buffer + publish-after-B2 prevents producer overrun.
__device__ __forceinline__ u64 aload64(const u64* p) {
    return __hip_atomic_load(p, __ATOMIC_RELAXED, __HIP_MEMORY_SCOPE_AGENT);
}
__device__ __forceinline__ void astore64(u64* p, u64 v) {
    __hip_atomic_store(p, v, __ATOMIC_RELAXED, __HIP_MEMORY_SCOPE_AGENT);
}

// ===================== Encoder =====================
// 256 blocks of 256 threads (1 wave/SIMD -> full 512-reg budget). Pair p =
// (dir,batch); half k owns hidden units [k*128,k*128+128), all 4 gates.
// Thread t owns rows t (gates 0/1) and t+512 (gates 2/3); shares broadcasts.
// Exchange: EVERY wave polls peer's 64 tagged u64 slots per-lane into registers
// (no LDS staging, no extra barrier); poll issued before phase-1 dots.
// 2 barriers/step: B2 (gates ready) and B3 (state updated).
__global__ __launch_bounds__(256, 1) void enc_kernel(
    const float* __restrict__ x,
    const float* __restrict__ WihF, const float* __restrict__ WhhF,
    const float* __restrict__ bihF, const float* __restrict__ bhhF,
    const float* __restrict__ WihB, const float* __restrict__ WhhB,
    const float* __restrict__ bihB, const float* __restrict__ bhhB,
    float* __restrict__ hF, float* __restrict__ hB,
    u64* __restrict__ xch,    // [128 pairs][2 halves][2 parity][64]
    int T)
{
    const int t    = threadIdx.x;
    const int lane = t & 63;
    const int g    = blockIdx.x;
    const int half = (g >> 3) & 1;               // pair-mates g and g^8
    const int p    = ((g >> 4) << 3) | (g & 7);  // pair id 0..127
    const int rev  = p >> 6;
    const int b    = p & 63;

    const int ug = t & 127;
    const int rA = (t >> 7) * Hc + half * 128 + ug;        // gate 0/1 row
    const int rB = ((t >> 7) + 2) * Hc + half * 128 + ug;  // gate 2/3 row

    const float* Wih = rev ? WihB : WihF;
    const float* Whh = rev ? WhhB : WhhF;
    const float* bih = rev ? bihB : bihF;
    const float* bhh = rev ? bhhB : bhhF;

    __shared__ u32   s_z[192];   // [0:64) own h pairs, [64:192) x parity 2x64
    __shared__ float s_g[512];

    u32 whAo[64], whAp[64], wiA[64];
    u32 whBo[64], whBp[64], wiB[64];
    {
        const int ob = half * 64, pb2 = (half ^ 1) * 64;
        const float* wrA = Whh + (size_t)rA * Hc;
        const float* wrB = Whh + (size_t)rB * Hc;
#pragma unroll
        for (int j = 0; j < 64; j++) {
            whAo[j] = pk_rne(wrA[2*(ob+j)],  wrA[2*(ob+j)+1]);
            whBo[j] = pk_rne(wrB[2*(ob+j)],  wrB[2*(ob+j)+1]);
            whAp[j] = pk_rne(wrA[2*(pb2+j)], wrA[2*(pb2+j)+1]);
            whBp[j] = pk_rne(wrB[2*(pb2+j)], wrB[2*(pb2+j)+1]);
        }
        const float* irA = Wih + (size_t)rA * Ic;
        const float* irB = Wih + (size_t)rB * Ic;
#pragma unroll
        for (int j = 0; j < 64; j++) {
            wiA[j] = pk_rne(irA[2*j], irA[2*j+1]);
            wiB[j] = pk_rne(irB[2*j], irB[2*j+1]);
        }
    }
    const float biasA = bih[rA] + bhh[rA];
    const float biasB = bih[rB] + bhh[rB];

    u64* xch_self = xch + ((size_t)(p * 2 + half)) * 128;        // 2 parity x 64
    u64* xch_peer = xch + ((size_t)(p * 2 + (half ^ 1))) * 128;

    if (t < 64) s_z[t] = 0u;      // h0 = 0 (own pairs)
    if (t >= 64 && t < 128) {     // x step 0 -> slot 0
        int m = t - 64;
        int ts0 = rev ? (T - 1) : 0;
        const float* xp = x + ((size_t)b * T + ts0) * Ic + 2 * m;
        s_z[64 + m] = pk_rne(xp[0], xp[1]);
    }
    if (t >= 128 && t < 192) {    // x step 1 -> slot 1
        int m = t - 128;
        int ts1 = rev ? (T - 2) : 1;
        const float* xp = x + ((size_t)b * T + ts1) * Ic + 2 * m;
        s_z[128 + m] = pk_rne(xp[0], xp[1]);
    }
    __syncthreads();

    float c0 = 0.f, c1 = 0.f;   // t<64: cells for units 2t, 2t+1 of own half
    for (int s = 0; s < T; s++) {
        const u64* pslot = &xch_peer[(s & 1) * 64 + lane];
        u64 pv = 0;
        if (s > 0) pv = aload64(pslot);   // early issue; checked after phase 1

        // ---- phase 1: x-dots + own-h dots ----
        u32 vzx = s_z[64 + (s & 1) * 64 + lane];
        u32 vzo = s_z[lane];
        float aA0 = biasA, aA1 = 0.f, aA2 = 0.f, aA3 = 0.f;
        float aB0 = biasB, aB1 = 0.f, aB2 = 0.f, aB3 = 0.f;
#pragma unroll
        for (int k = 0; k < 64; k += 4) {
            u32 h0 = rl(vzx, k+0), h1 = rl(vzx, k+1), h2 = rl(vzx, k+2), h3 = rl(vzx, k+3);
            aA0 = dot2acc(h0, wiA[k+0], aA0); aB0 = dot2acc(h0, wiB[k+0], aB0);
            aA1 = dot2acc(h1, wiA[k+1], aA1); aB1 = dot2acc(h1, wiB[k+1], aB1);
            aA2 = dot2acc(h2, wiA[k+2], aA2); aB2 = dot2acc(h2, wiB[k+2], aB2);
            aA3 = dot2acc(h3, wiA[k+3], aA3); aB3 = dot2acc(h3, wiB[k+3], aB3);
        }
#pragma unroll
        for (int k = 0; k < 64; k += 4) {
            u32 h0 = rl(vzo, k+0), h1 = rl(vzo, k+1), h2 = rl(vzo, k+2), h3 = rl(vzo, k+3);
            aA0 = dot2acc(h0, whAo[k+0], aA0); aB0 = dot2acc(h0, whBo[k+0], aB0);
            aA1 = dot2acc(h1, whAo[k+1], aA1); aB1 = dot2acc(h1, whBo[k+1], aB1);
            aA2 = dot2acc(h2, whAo[k+2], aA2); aB2 = dot2acc(h2, whBo[k+2], aB2);
            aA3 = dot2acc(h3, whAo[k+3], aA3); aB3 = dot2acc(h3, whBo[k+3], aB3);
        }
        // per-lane spin (tag rides with payload; tag == s exactly on exit)
        u32 vzp = 0u;
        if (s > 0) {
            while ((u32)(pv >> 32) < (u32)s) {
                __builtin_amdgcn_s_sleep(1);
                pv = aload64(pslot);
            }
            vzp = (u32)pv;
        }
        // ---- phase 2: peer-h dots ----
#pragma unroll
        for (int k = 0; k < 64; k += 4) {
            u32 h0 = rl(vzp, k+0), h1 = rl(vzp, k+1), h2 = rl(vzp, k+2), h3 = rl(vzp, k+3);
            aA0 = dot2acc(h0, whAp[k+0], aA0); aB0 = dot2acc(h0, whBp[k+0], aB0);
            aA1 = dot2acc(h1, whAp[k+1], aA1); aB1 = dot2acc(h1, whBp[k+1], aB1);
            aA2 = dot2acc(h2, whAp[k+2], aA2); aB2 = dot2acc(h2, whBp[k+2], aB2);
            aA3 = dot2acc(h3, whAp[k+3], aA3); aB3 = dot2acc(h3, whBp[k+3], aB3);
        }
        s_g[t]       = (aA0 + aA1) + (aA2 + aA3);
        s_g[t + 256] = (aB0 + aB1) + (aB2 + aB3);
        __syncthreads();   // B2: gates ready; all waves consumed peer tag s

        const int notlast = (s + 1 < T);
        if (t < 64) {   // cell + publish ASAP
            float i0 = s_g[2*t],     i1 = s_g[2*t+1];
            float f0 = s_g[128+2*t], f1 = s_g[128+2*t+1];
            float g0 = s_g[256+2*t], g1 = s_g[256+2*t+1];
            float o0 = s_g[384+2*t], o1 = s_g[384+2*t+1];
            c0 = sigm(f0)*c0 + sigm(i0)*tanh_f(g0);
            c1 = sigm(f1)*c1 + sigm(i1)*tanh_f(g1);
            float h0 = sigm(o0)*tanh_f(c0);
            float h1 = sigm(o1)*tanh_f(c1);
            u32 hp = pk_rne(h0, h1);
            s_z[t] = hp;
            if (notlast) {
                astore64(&xch_self[((s+1) & 1) * 64 + t],
                         ((u64)(u32)(s + 1) << 32) | (u64)hp);
            } else {
                float* ho = (rev ? hB : hF) + (size_t)b * Hc + half * 128 + 2 * t;
                ho[0] = h0; ho[1] = h1;
            }
        } else if (t < 128) {   // x prefetch depth 2
            int sn = s + 2;
            if (sn < T) {
                int m = t - 64;
                int ts = rev ? (T - 1 - sn) : sn;
                const float* xp = x + ((size_t)b * T + ts) * Ic + 2 * m;
                s_z[64 + (sn & 1) * 64 + m] = pk_rne(xp[0], xp[1]);
            }
        }
        __syncthreads();   // B3: state updated
    }
}

// ===================== Latent bottleneck =====================
__global__ void lat_kernel(const float* __restrict__ hF, const float* __restrict__ hB,
                           const float* __restrict__ latW, const float* __restrict__ latb,
                           const float* __restrict__ l2hW, const float* __restrict__ l2hb,
                           float* __restrict__ hidden)
{
    int b = blockIdx.x, t = threadIdx.x;  // 256 threads
    __shared__ float s_hn[512];
    __shared__ float s_lat[64];
    s_hn[t]       = hF[(size_t)b * Hc + t];
    s_hn[256 + t] = hB[(size_t)b * Hc + t];
    __syncthreads();
    if (t < 64) {
        float a = latb[t];
        const float* wp = latW + (size_t)t * 512;
        for (int k = 0; k < 512; k++) a += wp[k] * s_hn[k];
        s_lat[t] = a;
    }
    __syncthreads();
    float a = l2hb[t];
    const float* wp = l2hW + (size_t)t * 64;
#pragma unroll
    for (int k = 0; k < 64; k++) a += wp[k] * s_lat[k];
    hidden[(size_t)b * Hc + t] = a;
}

// ===================== Decoder =====================
// 128 blocks of 256 threads. Recurrence as encoder. Projection of h_s runs
// AFTER B2 (register-sourced: vzo/vzp), concurrent with wave0's cell+publish;
// s_op parity double-buffered; decoded[s-2] stored at iteration s by wave 2.
__global__ __launch_bounds__(256, 1) void dec_kernel(
    const float* __restrict__ x,
    const float* __restrict__ Wih, const float* __restrict__ Whh,
    const float* __restrict__ bih, const float* __restrict__ bhh,
    const float* __restrict__ outW, const float* __restrict__ outb,
    const float* __restrict__ hidden, float* __restrict__ out,
    u64* __restrict__ xch,    // [64 batches][2 halves][2 parity][64]
    int T)
{
    const int t    = threadIdx.x;
    const int lane = t & 63;
    const int g    = blockIdx.x;
    const int half = (g >> 3) & 1;
    const int b    = ((g >> 4) << 3) | (g & 7);   // 0..63
    const int Ts   = T - 1;

    const int ug = t & 127;
    const int rA = (t >> 7) * Hc + half * 128 + ug;
    const int rB = ((t >> 7) + 2) * Hc + half * 128 + ug;

    __shared__ u32   s_z[192];        // [0:64) own h pairs, [64:192) x parity
    __shared__ float s_g[512];
    __shared__ float s_op[2][256];    // projection partials, parity dbuf
    __shared__ u32   s_ow[32 * 256];  // own 64 outW rows packed, keyed by t

    u32 whAo[64], whAp[64], wiA[64];
    u32 whBo[64], whBp[64], wiB[64];
    {
        const int ob = half * 64, pb2 = (half ^ 1) * 64;
        const float* wrA = Whh + (size_t)rA * Hc;
        const float* wrB = Whh + (size_t)rB * Hc;
#pragma unroll
        for (int j = 0; j < 64; j++) {
            whAo[j] = pk_rne(wrA[2*(ob+j)],  wrA[2*(ob+j)+1]);
            whBo[j] = pk_rne(wrB[2*(ob+j)],  wrB[2*(ob+j)+1]);
            whAp[j] = pk_rne(wrA[2*(pb2+j)], wrA[2*(pb2+j)+1]);
            whBp[j] = pk_rne(wrB[2*(pb2+j)], wrB[2*(pb2+j)+1]);
        }
        const float* irA = Wih + (size_t)rA * Ic;
        const float* irB = Wih + (size_t)rB * Ic;
#pragma unroll
        for (int j = 0; j < 64; j++) {
            wiA[j] = pk_rne(irA[2*j], irA[2*j+1]);
            wiB[j] = pk_rne(irB[2*j], irB[2*j+1]);
        }
    }
    const float biasA = bih[rA] + bhh[rA];
    const float biasB = bih[rB] + bhh[rB];

    {   // stage own half's 64 outW rows: thread t = row half*64+(t&63), chunk t>>6
        const float* op = outW + (size_t)(half * 64 + (t & 63)) * Hc + (size_t)(t >> 6) * 64;
#pragma unroll
        for (int j = 0; j < 32; j++)
            s_ow[j * 256 + t] = pk_rne(op[2*j], op[2*j+1]);
    }
    const float outb_r = (t >= 128 && t < 192) ? outb[half * 64 + (t - 128)] : 0.f;

    u64* xch_self = xch + ((size_t)(b * 2 + half)) * 128;
    u64* xch_peer = xch + ((size_t)(b * 2 + (half ^ 1))) * 128;

    if (t < 64) {   // own h0 pairs
        const float* hp = hidden + (size_t)b * Hc + half * 128 + 2 * t;
        s_z[t] = pk_rne(hp[0], hp[1]);
    }
    if (t >= 64 && t < 128) {   // x step 0 -> slot 0
        int m = t - 64;
        const float* xp = x + ((size_t)b * T) * Ic + 2 * m;
        s_z[64 + m] = pk_rne(xp[0], xp[1]);
    }
    if (t >= 128 && t < 192) {   // x step 1 -> slot 1
        int m = t - 128;
        const float* xp = x + ((size_t)b * T + 1) * Ic + 2 * m;
        s_z[128 + m] = pk_rne(xp[0], xp[1]);
    }
    u32 vzp_init;
    {   // peer h0 pairs, per lane (register)
        const float* hp = hidden + (size_t)b * Hc + (half ^ 1) * 128 + 2 * lane;
        vzp_init = pk_rne(hp[0], hp[1]);
    }
    __syncthreads();

    float c0 = 0.f, c1 = 0.f;
    for (int s = 0; s < Ts; s++) {
        const u64* pslot = &xch_peer[(s & 1) * 64 + lane];
        u64 pv = 0;
        if (s > 0) pv = aload64(pslot);   // early issue

        u32 vzx = s_z[64 + (s & 1) * 64 + lane];
        u32 vzo = s_z[lane];
        float aA0 = biasA, aA1 = 0.f, aA2 = 0.f, aA3 = 0.f;
        float aB0 = biasB, aB1 = 0.f, aB2 = 0.f, aB3 = 0.f;
#pragma unroll
        for (int k = 0; k < 64; k += 4) {
            u32 h0 = rl(vzx, k+0), h1 = rl(vzx, k+1), h2 = rl(vzx, k+2), h3 = rl(vzx, k+3);
            aA0 = dot2acc(h0, wiA[k+0], aA0); aB0 = dot2acc(h0, wiB[k+0], aB0);
            aA1 = dot2acc(h1, wiA[k+1], aA1); aB1 = dot2acc(h1, wiB[k+1], aB1);
            aA2 = dot2acc(h2, wiA[k+2], aA2); aB2 = dot2acc(h2, wiB[k+2], aB2);
            aA3 = dot2acc(h3, wiA[k+3], aA3); aB3 = dot2acc(h3, wiB[k+3], aB3);
        }
#pragma unroll
        for (int k = 0; k < 64; k += 4) {
            u32 h0 = rl(vzo, k+0), h1 = rl(vzo, k+1), h2 = rl(vzo, k+2), h3 = rl(vzo, k+3);
            aA0 = dot2acc(h0, whAo[k+0], aA0); aB0 = dot2acc(h0, whBo[k+0], aB0);
            aA1 = dot2acc(h1, whAo[k+1], aA1); aB1 = dot2acc(h1, whBo[k+1], aB1);
            aA2 = dot2acc(h2, whAo[k+2], aA2); aB2 = dot2acc(h2, whBo[k+2], aB2);
            aA3 = dot2acc(h3, whAo[k+3], aA3); aB3 = dot2acc(h3, whBo[k+3], aB3);
        }
        u32 vzp;
        if (s > 0) {
            while ((u32)(pv >> 32) < (u32)s) {
                __builtin_amdgcn_s_sleep(1);
                pv = aload64(pslot);
            }
            vzp = (u32)pv;
        } else vzp = vzp_init;
#pragma unroll
        for (int k = 0; k < 64; k += 4) {
            u32 h0 = rl(vzp, k+0), h1 = rl(vzp, k+1), h2 = rl(vzp, k+2), h3 = rl(vzp, k+3);
            aA0 = dot2acc(h0, whAp[k+0], aA0); aB0 = dot2acc(h0, whBp[k+0], aB0);
            aA1 = dot2acc(h1, whAp[k+1], aA1); aB1 = dot2acc(h1, whBp[k+1], aB1);
            aA2 = dot2acc(h2, whAp[k+2], aA2); aB2 = dot2acc(h2, whBp[k+2], aB2);
            aA3 = dot2acc(h3, whAp[k+3], aA3); aB3 = dot2acc(h3, whBp[k+3], aB3);
        }
        s_g[t]       = (aA0 + aA1) + (aA2 + aA3);
        s_g[t + 256] = (aB0 + aB1) + (aB2 + aB3);
        __syncthreads();   // B2

        if (t < 64) {   // cell + publish ASAP (every step; peer tail needs h_Ts)
            float i0 = s_g[2*t],     i1 = s_g[2*t+1];
            float f0 = s_g[128+2*t], f1 = s_g[128+2*t+1];
            float g0 = s_g[256+2*t], g1 = s_g[256+2*t+1];
            float o0 = s_g[384+2*t], o1 = s_g[384+2*t+1];
            c0 = sigm(f0)*c0 + sigm(i0)*tanh_f(g0);
            c1 = sigm(f1)*c1 + sigm(i1)*tanh_f(g1);
            float h0 = sigm(o0)*tanh_f(c0);
            float h1 = sigm(o1)*tanh_f(c1);
            u32 hp = pk_rne(h0, h1);
            s_z[t] = hp;
            astore64(&xch_self[((s+1) & 1) * 64 + t],
                     ((u64)(u32)(s + 1) << 32) | (u64)hp);
        } else if (t < 128) {   // x prefetch depth 2
            int sn = s + 2;
            if (sn < Ts) {
                int m = t - 64;
                const float* xp = x + ((size_t)b * T + sn) * Ic + 2 * m;
                s_z[64 + (sn & 1) * 64 + m] = pk_rne(xp[0], xp[1]);
            }
        } else if (t < 192 && s >= 2) {   // store decoded[s-2] from other parity
            int rr = t - 128;
            const float* sp = s_op[(s - 1) & 1];
            float y = outb_r + ((sp[rr*4+0] + sp[rr*4+1]) + (sp[rr*4+2] + sp[rr*4+3]));
            out[((size_t)b * Ts + (s - 2)) * Ic + half * 64 + rr] = y;
        }
        if (s > 0) {   // projection of h_s (registers only) -> s_op[s&1]
            const int ksl = t >> 6;             // wave-uniform 0..3
            const int kb  = (ksl & 1) * 32;
            u32 vplo = half ? vzp : vzo;        // global h pairs 0..63
            u32 vphi = half ? vzo : vzp;        // global h pairs 64..127
            float p0 = 0.f, p1 = 0.f;
#pragma unroll
            for (int j = 0; j < 32; j += 2) {
                u32 h0b = (ksl < 2) ? rl(vplo, kb + j)     : rl(vphi, kb + j);
                u32 h1b = (ksl < 2) ? rl(vplo, kb + j + 1) : rl(vphi, kb + j + 1);
                p0 = dot2acc(h0b, s_ow[(j)     * 256 + t], p0);
                p1 = dot2acc(h1b, s_ow[(j + 1) * 256 + t], p1);
            }
            s_op[s & 1][(t & 63) * 4 + ksl] = p0 + p1;
        }
        __syncthreads();   // B3
    }

    // tail 1: pending decoded[Ts-2] (proj written at iter Ts-1)
    if (t >= 128 && t < 192) {
        int rr = t - 128;
        const float* sp = s_op[(Ts - 1) & 1];
        float y = outb_r + ((sp[rr*4+0] + sp[rr*4+1]) + (sp[rr*4+2] + sp[rr*4+3]));
        out[((size_t)b * Ts + (Ts - 2)) * Ic + half * 64 + rr] = y;
    }
    // tail 2: decoded[Ts-1] from h_Ts (own h in s_z; peer via tag Ts)
    {
        u32 vzo2 = s_z[lane];
        const u64* pslot = &xch_peer[(Ts & 1) * 64 + lane];
        u64 pv = aload64(pslot);
        while ((u32)(pv >> 32) < (u32)Ts) {
            __builtin_amdgcn_s_sleep(1);
            pv = aload64(pslot);
        }
        u32 vzp2 = (u32)pv;
        const int ksl = t >> 6;
        const int kb  = (ksl & 1) * 32;
        u32 vplo = half ? vzp2 : vzo2;
        u32 vphi = half ? vzo2 : vzp2;
        float p0 = 0.f, p1 = 0.f;
#pragma unroll
        for (int j = 0; j < 32; j += 2) {
            u32 h0b = (ksl < 2) ? rl(vplo, kb + j)     : rl(vphi, kb + j);
            u32 h1b = (ksl < 2) ? rl(vplo, kb + j + 1) : rl(vphi, kb + j + 1);
            p0 = dot2acc(h0b, s_ow[(j)     * 256 + t], p0);
            p1 = dot2acc(h1b, s_ow[(j + 1) * 256 + t], p1);
        }
        s_op[Ts & 1][(t & 63) * 4 + ksl] = p0 + p1;
    }
    __syncthreads();
    if (t >= 128 && t < 192) {
        int rr = t - 128;
        const float* sp = s_op[Ts & 1];
        float y = outb_r + ((sp[rr*4+0] + sp[rr*4+1]) + (sp[rr*4+2] + sp[rr*4+3]));
        out[((size_t)b * Ts + (Ts - 1)) * Ic + half * 64 + rr] = y;
    }
}

extern "C" void kernel_launch(void* const* d_in, const int* in_sizes, int n_in,
                              void* d_out, int out_size, void* d_ws, size_t ws_size,
                              hipStream_t stream)
{
    const float* x    = (const float*)d_in[0];
    const float* WihF = (const float*)d_in[1];
    const float* WhhF = (const float*)d_in[2];
    const float* bihF = (const float*)d_in[3];
    const float* bhhF = (const float*)d_in[4];
    const float* WihB = (const float*)d_in[5];
    const float* WhhB = (const float*)d_in[6];
    const float* bihB = (const float*)d_in[7];
    const float* bhhB = (const float*)d_in[8];
    const float* latW = (const float*)d_in[9];
    const float* latb = (const float*)d_in[10];
    const float* l2hW = (const float*)d_in[11];
    const float* l2hb = (const float*)d_in[12];
    const float* dWih = (const float*)d_in[13];
    const float* dWhh = (const float*)d_in[14];
    const float* dbih = (const float*)d_in[15];
    const float* dbhh = (const float*)d_in[16];
    const float* outW = (const float*)d_in[17];
    const float* outb = (const float*)d_in[18];

    const int T = in_sizes[0] / (64 * Ic);  // 4096

    float* ws  = (float*)d_ws;
    float* hFp = ws;                 // [64,256]
    float* hBp = ws + 16384;         // [64,256]
    float* hid = ws + 32768;         // [64,256]
    u64* encXch = (u64*)(ws + 49152);   // 128*2*2*64 = 32768 u64
    u64* decXch = encXch + 32768;       // 64*2*2*64  = 16384 u64

    // zero all tags (graph replay must restart deterministically)
    hipMemsetAsync(encXch, 0, (32768 + 16384) * sizeof(u64), stream);

    enc_kernel<<<256, 256, 0, stream>>>(x, WihF, WhhF, bihF, bhhF,
                                        WihB, WhhB, bihB, bhhB,
                                        hFp, hBp, encXch, T);
    lat_kernel<<<64, 256, 0, stream>>>(hFp, hBp, latW, latb, l2hW, l2hb, hid);
    dec_kernel<<<128, 256, 0, stream>>>(x, dWih, dWhh, dbih, dbhh,
                                        outW, outb, hid, (float*)d_out,
                                        decXch, T);
}

// Round 11
// 30191.150 us; speedup vs baseline: 1.6167x; 1.0060x over previous
//
#include <hip/hip_runtime.h>
#include <stdint.h>

#define Ic 128   // input size
#define Hc 256   // hidden size

typedef uint32_t u32;
typedef unsigned long long u64;
using half2v = __attribute__((ext_vector_type(2))) _Float16;

__device__ __forceinline__ u32 pk_rne(float a, float b) {
    _Float16 lo = (_Float16)a, hi = (_Float16)b;
    return (u32)__builtin_bit_cast(uint16_t, lo) |
           ((u32)__builtin_bit_cast(uint16_t, hi) << 16);
}
__device__ __forceinline__ float dot2acc(u32 a, u32 b, float c) {
    return __builtin_amdgcn_fdot2(__builtin_bit_cast(half2v, a),
                                  __builtin_bit_cast(half2v, b), c, false);
}
__device__ __forceinline__ u32 rl(u32 v, int k) {
    return (u32)__builtin_amdgcn_readlane((int)v, k);
}
__device__ __forceinline__ float sigm(float x) {
    return __builtin_amdgcn_rcpf(1.f + __expf(-x));
}
__device__ __forceinline__ float tanh_f(float x) {
    float e = __expf(-2.f * __builtin_fabsf(x));
    float t = (1.f - e) * __builtin_amdgcn_rcpf(1.f + e);
    return __builtin_copysignf(t, x);
}
__device__ __forceinline__ u64 aload64(const u64* p) {
    return __hip_atomic_load(p, __ATOMIC_RELAXED, __HIP_MEMORY_SCOPE_AGENT);
}
__device__ __forceinline__ void astore64(u64* p, u64 v) {
    __hip_atomic_store(p, v, __ATOMIC_RELAXED, __HIP_MEMORY_SCOPE_AGENT);
}
// Raw barrier: LDS-ordering only. Does NOT drain vmcnt -> global loads/stores
// (x prefetch, publish, out) stay in flight across it. sched_barrier fences
// prevent the scheduler from moving LDS ops across (guide rule #18).
__device__ __forceinline__ void block_sync_lds() {
    asm volatile("s_waitcnt lgkmcnt(0)" ::: "memory");
    __builtin_amdgcn_sched_barrier(0);
    __builtin_amdgcn_s_barrier();
    __builtin_amdgcn_sched_barrier(0);
}

// ===================== Encoder =====================
// 256 blocks of 256 threads (1 wave/SIMD, full 512-reg budget). Pair p =
// (dir,batch); half k owns units [k*128,+128). Wave w owns ALL 4 gates of its
// 32 units: lane j<32 -> rows (i,g) of unit w*32+j; lane 32+j -> rows (f,o).
// Cell = 2 intra-wave shfls (no LDS gates, no mid barrier); each wave publishes
// its 16 h-pair tagged slots as soon as its dots finish. ONE raw barrier/step.
// x loaded to registers one step ahead (latency hidden, nothing drains at bar).
__global__ __launch_bounds__(256, 1) void enc_kernel(
    const float* __restrict__ x,
    const float* __restrict__ WihF, const float* __restrict__ WhhF,
    const float* __restrict__ bihF, const float* __restrict__ bhhF,
    const float* __restrict__ WihB, const float* __restrict__ WhhB,
    const float* __restrict__ bihB, const float* __restrict__ bhhB,
    float* __restrict__ hF, float* __restrict__ hB,
    u64* __restrict__ xch,    // [128 pairs][2 halves][2 parity][64]
    int T)
{
    const int t    = threadIdx.x;
    const int lane = t & 63;
    const int w    = t >> 6;
    const int j    = lane & 31;
    const int sel  = lane >> 5;                  // 0: rows (i,g), 1: rows (f,o)
    const int g    = blockIdx.x;
    const int half = (g >> 3) & 1;               // pair-mates g and g^8
    const int p    = ((g >> 4) << 3) | (g & 7);  // pair id 0..127
    const int rev  = p >> 6;
    const int b    = p & 63;

    const int u  = half * 128 + w * 32 + j;      // global hidden unit
    const int rA = sel * Hc + u;                 // gate 0(i) or 1(f)
    const int rB = (sel + 2) * Hc + u;           // gate 2(g) or 3(o)

    const float* Wih = rev ? WihB : WihF;
    const float* Whh = rev ? WhhB : WhhF;
    const float* bih = rev ? bihB : bihF;
    const float* bhh = rev ? bhhB : bhhF;

    __shared__ u32 s_zh[2][64];   // own-half h pairs, parity double-buffered

    u32 whAo[64], whAp[64], wiA[64];
    u32 whBo[64], whBp[64], wiB[64];
    {
        const int ob = half * 64, pb2 = (half ^ 1) * 64;
        const float* wrA = Whh + (size_t)rA * Hc;
        const float* wrB = Whh + (size_t)rB * Hc;
#pragma unroll
        for (int k = 0; k < 64; k++) {
            whAo[k] = pk_rne(wrA[2*(ob+k)],  wrA[2*(ob+k)+1]);
            whBo[k] = pk_rne(wrB[2*(ob+k)],  wrB[2*(ob+k)+1]);
            whAp[k] = pk_rne(wrA[2*(pb2+k)], wrA[2*(pb2+k)+1]);
            whBp[k] = pk_rne(wrB[2*(pb2+k)], wrB[2*(pb2+k)+1]);
        }
        const float* irA = Wih + (size_t)rA * Ic;
        const float* irB = Wih + (size_t)rB * Ic;
#pragma unroll
        for (int k = 0; k < 64; k++) {
            wiA[k] = pk_rne(irA[2*k], irA[2*k+1]);
            wiB[k] = pk_rne(irB[2*k], irB[2*k+1]);
        }
    }
    const float biasA = bih[rA] + bhh[rA];
    const float biasB = bih[rB] + bhh[rB];

    u64* xch_self = xch + ((size_t)(p * 2 + half)) * 128;        // 2 parity x 64
    u64* xch_peer = xch + ((size_t)(p * 2 + (half ^ 1))) * 128;

    if (t < 64) { s_zh[0][t] = 0u; s_zh[1][t] = 0u; }   // h0 = 0
    float2 xn;
    {   // preload x for step 0 (per-wave lane slice)
        int ts0 = rev ? (T - 1) : 0;
        xn = *(const float2*)(x + ((size_t)b * T + ts0) * Ic + 2 * lane);
    }
    __syncthreads();

    float c = 0.f;   // lanes j<32: cell of unit u
    for (int s = 0; s < T; s++) {
        u32 vzx = pk_rne(xn.x, xn.y);          // waited: load had a full iter
        int sn = s + 1;
        if (sn < T) {   // issue next x load (consumed at next iter head)
            int ts = rev ? (T - 1 - sn) : sn;
            xn = *(const float2*)(x + ((size_t)b * T + ts) * Ic + 2 * lane);
        }
        const u64* pslot = &xch_peer[(s & 1) * 64 + lane];
        u64 pv = 0;
        if (s > 0) pv = aload64(pslot);        // early issue

        u32 vzo = s_zh[s & 1][lane];
        float aA0 = biasA, aA1 = 0.f, aA2 = 0.f, aA3 = 0.f;
        float aB0 = biasB, aB1 = 0.f, aB2 = 0.f, aB3 = 0.f;
#pragma unroll
        for (int k = 0; k < 64; k += 4) {
            u32 h0 = rl(vzx, k+0), h1 = rl(vzx, k+1), h2 = rl(vzx, k+2), h3 = rl(vzx, k+3);
            aA0 = dot2acc(h0, wiA[k+0], aA0); aB0 = dot2acc(h0, wiB[k+0], aB0);
            aA1 = dot2acc(h1, wiA[k+1], aA1); aB1 = dot2acc(h1, wiB[k+1], aB1);
            aA2 = dot2acc(h2, wiA[k+2], aA2); aB2 = dot2acc(h2, wiB[k+2], aB2);
            aA3 = dot2acc(h3, wiA[k+3], aA3); aB3 = dot2acc(h3, wiB[k+3], aB3);
        }
#pragma unroll
        for (int k = 0; k < 64; k += 4) {
            u32 h0 = rl(vzo, k+0), h1 = rl(vzo, k+1), h2 = rl(vzo, k+2), h3 = rl(vzo, k+3);
            aA0 = dot2acc(h0, whAo[k+0], aA0); aB0 = dot2acc(h0, whBo[k+0], aB0);
            aA1 = dot2acc(h1, whAo[k+1], aA1); aB1 = dot2acc(h1, whBo[k+1], aB1);
            aA2 = dot2acc(h2, whAo[k+2], aA2); aB2 = dot2acc(h2, whBo[k+2], aB2);
            aA3 = dot2acc(h3, whAo[k+3], aA3); aB3 = dot2acc(h3, whBo[k+3], aB3);
        }
        u32 vzp = 0u;
        if (s > 0) {   // per-lane spin on tagged slot
            while ((u32)(pv >> 32) < (u32)s) {
                __builtin_amdgcn_s_sleep(1);
                pv = aload64(pslot);
            }
            vzp = (u32)pv;
        }
#pragma unroll
        for (int k = 0; k < 64; k += 4) {
            u32 h0 = rl(vzp, k+0), h1 = rl(vzp, k+1), h2 = rl(vzp, k+2), h3 = rl(vzp, k+3);
            aA0 = dot2acc(h0, whAp[k+0], aA0); aB0 = dot2acc(h0, whBp[k+0], aB0);
            aA1 = dot2acc(h1, whAp[k+1], aA1); aB1 = dot2acc(h1, whBp[k+1], aB1);
            aA2 = dot2acc(h2, whAp[k+2], aA2); aB2 = dot2acc(h2, whBp[k+2], aB2);
            aA3 = dot2acc(h3, whAp[k+3], aA3); aB3 = dot2acc(h3, whBp[k+3], aB3);
        }
        float aAs = (aA0 + aA1) + (aA2 + aA3);   // lanes<32: i(u); lanes>=32: f(u)
        float aBs = (aB0 + aB1) + (aB2 + aB3);   // lanes<32: g(u); lanes>=32: o(u)

        // wave-local cell: fetch f,o from lane 32+j
        float f_ = __shfl(aAs, 32 + j);
        float o_ = __shfl(aBs, 32 + j);
        c = sigm(f_) * c + sigm(aAs) * tanh_f(aBs);
        float h = sigm(o_) * tanh_f(c);
        // pack pair q from lanes 2q, 2q+1
        float he = __shfl(h, 2 * (lane & 15));
        float ho = __shfl(h, 2 * (lane & 15) + 1);
        u32 hp = pk_rne(he, ho);
        const int notlast = (s + 1 < T);
        if (lane < 16) {
            int q = w * 16 + lane;
            s_zh[(s + 1) & 1][q] = hp;
            if (notlast)
                astore64(&xch_self[((s + 1) & 1) * 64 + q],
                         ((u64)(u32)(s + 1) << 32) | (u64)hp);
        }
        if (!notlast && lane < 32) {   // final h -> workspace (float)
            (rev ? hB : hF)[(size_t)b * Hc + u] = h;
        }
        block_sync_lds();
    }
}

// ===================== Latent bottleneck =====================
__global__ void lat_kernel(const float* __restrict__ hF, const float* __restrict__ hB,
                           const float* __restrict__ latW, const float* __restrict__ latb,
                           const float* __restrict__ l2hW, const float* __restrict__ l2hb,
                           float* __restrict__ hidden)
{
    int b = blockIdx.x, t = threadIdx.x;  // 256 threads
    __shared__ float s_hn[512];
    __shared__ float s_lat[64];
    s_hn[t]       = hF[(size_t)b * Hc + t];
    s_hn[256 + t] = hB[(size_t)b * Hc + t];
    __syncthreads();
    if (t < 64) {
        float a = latb[t];
        const float* wp = latW + (size_t)t * 512;
        for (int k = 0; k < 512; k++) a += wp[k] * s_hn[k];
        s_lat[t] = a;
    }
    __syncthreads();
    float a = l2hb[t];
    const float* wp = l2hW + (size_t)t * 64;
#pragma unroll
    for (int k = 0; k < 64; k++) a += wp[k] * s_lat[k];
    hidden[(size_t)b * Hc + t] = a;
}

// ===================== Decoder =====================
// 128 blocks of 256 threads. Recurrence as encoder (wave-local cells).
// Projection of entering-h (h_s -> decoded[s-1]) by all lanes from registers;
// s_op parity dbuf; decoded[s-2] stored by lanes 32..47 of each wave.
__global__ __launch_bounds__(256, 1) void dec_kernel(
    const float* __restrict__ x,
    const float* __restrict__ Wih, const float* __restrict__ Whh,
    const float* __restrict__ bih, const float* __restrict__ bhh,
    const float* __restrict__ outW, const float* __restrict__ outb,
    const float* __restrict__ hidden, float* __restrict__ out,
    u64* __restrict__ xch,    // [64 batches][2 halves][2 parity][64]
    int T)
{
    const int t    = threadIdx.x;
    const int lane = t & 63;
    const int w    = t >> 6;
    const int j    = lane & 31;
    const int sel  = lane >> 5;
    const int g    = blockIdx.x;
    const int half = (g >> 3) & 1;
    const int b    = ((g >> 4) << 3) | (g & 7);   // 0..63
    const int Ts   = T - 1;

    const int u  = half * 128 + w * 32 + j;
    const int rA = sel * Hc + u;
    const int rB = (sel + 2) * Hc + u;

    __shared__ u32   s_zh[2][64];
    __shared__ float s_op[2][256];
    __shared__ u32   s_ow[32 * 256];   // own 64 outW rows packed, keyed by t

    u32 whAo[64], whAp[64], wiA[64];
    u32 whBo[64], whBp[64], wiB[64];
    {
        const int ob = half * 64, pb2 = (half ^ 1) * 64;
        const float* wrA = Whh + (size_t)rA * Hc;
        const float* wrB = Whh + (size_t)rB * Hc;
#pragma unroll
        for (int k = 0; k < 64; k++) {
            whAo[k] = pk_rne(wrA[2*(ob+k)],  wrA[2*(ob+k)+1]);
            whBo[k] = pk_rne(wrB[2*(ob+k)],  wrB[2*(ob+k)+1]);
            whAp[k] = pk_rne(wrA[2*(pb2+k)], wrA[2*(pb2+k)+1]);
            whBp[k] = pk_rne(wrB[2*(pb2+k)], wrB[2*(pb2+k)+1]);
        }
        const float* irA = Wih + (size_t)rA * Ic;
        const float* irB = Wih + (size_t)rB * Ic;
#pragma unroll
        for (int k = 0; k < 64; k++) {
            wiA[k] = pk_rne(irA[2*k], irA[2*k+1]);
            wiB[k] = pk_rne(irB[2*k], irB[2*k+1]);
        }
    }
    const float biasA = bih[rA] + bhh[rA];
    const float biasB = bih[rB] + bhh[rB];

    {   // stage own half's 64 outW rows: thread t = row half*64+(t&63), chunk t>>6
        const float* op = outW + (size_t)(half * 64 + (t & 63)) * Hc + (size_t)(t >> 6) * 64;
#pragma unroll
        for (int k = 0; k < 32; k++)
            s_ow[k * 256 + t] = pk_rne(op[2*k], op[2*k+1]);
    }
    const float outb_r = (lane >= 32 && lane < 48) ? outb[half * 64 + w * 16 + (lane - 32)] : 0.f;

    u64* xch_self = xch + ((size_t)(b * 2 + half)) * 128;
    u64* xch_peer = xch + ((size_t)(b * 2 + (half ^ 1))) * 128;

    if (t < 64) {   // own h0 pairs
        const float* hp = hidden + (size_t)b * Hc + half * 128 + 2 * t;
        u32 v = pk_rne(hp[0], hp[1]);
        s_zh[0][t] = v; s_zh[1][t] = v;
    }
    u32 vzp_init;
    {   // peer h0 pairs, per lane
        const float* hp = hidden + (size_t)b * Hc + (half ^ 1) * 128 + 2 * lane;
        vzp_init = pk_rne(hp[0], hp[1]);
    }
    float2 xn = *(const float2*)(x + ((size_t)b * T) * Ic + 2 * lane);  // step 0
    __syncthreads();

    float c = 0.f;
    for (int s = 0; s < Ts; s++) {
        u32 vzx = pk_rne(xn.x, xn.y);
        int sn = s + 1;
        if (sn < Ts)
            xn = *(const float2*)(x + ((size_t)b * T + sn) * Ic + 2 * lane);
        const u64* pslot = &xch_peer[(s & 1) * 64 + lane];
        u64 pv = 0;
        if (s > 0) pv = aload64(pslot);

        u32 vzo = s_zh[s & 1][lane];
        float aA0 = biasA, aA1 = 0.f, aA2 = 0.f, aA3 = 0.f;
        float aB0 = biasB, aB1 = 0.f, aB2 = 0.f, aB3 = 0.f;
#pragma unroll
        for (int k = 0; k < 64; k += 4) {
            u32 h0 = rl(vzx, k+0), h1 = rl(vzx, k+1), h2 = rl(vzx, k+2), h3 = rl(vzx, k+3);
            aA0 = dot2acc(h0, wiA[k+0], aA0); aB0 = dot2acc(h0, wiB[k+0], aB0);
            aA1 = dot2acc(h1, wiA[k+1], aA1); aB1 = dot2acc(h1, wiB[k+1], aB1);
            aA2 = dot2acc(h2, wiA[k+2], aA2); aB2 = dot2acc(h2, wiB[k+2], aB2);
            aA3 = dot2acc(h3, wiA[k+3], aA3); aB3 = dot2acc(h3, wiB[k+3], aB3);
        }
#pragma unroll
        for (int k = 0; k < 64; k += 4) {
            u32 h0 = rl(vzo, k+0), h1 = rl(vzo, k+1), h2 = rl(vzo, k+2), h3 = rl(vzo, k+3);
            aA0 = dot2acc(h0, whAo[k+0], aA0); aB0 = dot2acc(h0, whBo[k+0], aB0);
            aA1 = dot2acc(h1, whAo[k+1], aA1); aB1 = dot2acc(h1, whBo[k+1], aB1);
            aA2 = dot2acc(h2, whAo[k+2], aA2); aB2 = dot2acc(h2, whBo[k+2], aB2);
            aA3 = dot2acc(h3, whAo[k+3], aA3); aB3 = dot2acc(h3, whBo[k+3], aB3);
        }
        u32 vzp;
        if (s > 0) {
            while ((u32)(pv >> 32) < (u32)s) {
                __builtin_amdgcn_s_sleep(1);
                pv = aload64(pslot);
            }
            vzp = (u32)pv;
        } else vzp = vzp_init;
#pragma unroll
        for (int k = 0; k < 64; k += 4) {
            u32 h0 = rl(vzp, k+0), h1 = rl(vzp, k+1), h2 = rl(vzp, k+2), h3 = rl(vzp, k+3);
            aA0 = dot2acc(h0, whAp[k+0], aA0); aB0 = dot2acc(h0, whBp[k+0], aB0);
            aA1 = dot2acc(h1, whAp[k+1], aA1); aB1 = dot2acc(h1, whBp[k+1], aB1);
            aA2 = dot2acc(h2, whAp[k+2], aA2); aB2 = dot2acc(h2, whBp[k+2], aB2);
            aA3 = dot2acc(h3, whAp[k+3], aA3); aB3 = dot2acc(h3, whBp[k+3], aB3);
        }
        float aAs = (aA0 + aA1) + (aA2 + aA3);
        float aBs = (aB0 + aB1) + (aB2 + aB3);

        float f_ = __shfl(aAs, 32 + j);
        float o_ = __shfl(aBs, 32 + j);
        c = sigm(f_) * c + sigm(aAs) * tanh_f(aBs);
        float h = sigm(o_) * tanh_f(c);
        float he = __shfl(h, 2 * (lane & 15));
        float ho = __shfl(h, 2 * (lane & 15) + 1);
        u32 hp = pk_rne(he, ho);
        if (lane < 16) {   // publish ASAP (every step; peer tail needs h_Ts)
            int q = w * 16 + lane;
            s_zh[(s + 1) & 1][q] = hp;
            astore64(&xch_self[((s + 1) & 1) * 64 + q],
                     ((u64)(u32)(s + 1) << 32) | (u64)hp);
        }

        if (s > 0) {   // projection of entering h_s -> decoded[s-1] partials
            const int ksl = t >> 6;             // wave-uniform 0..3
            const int kb  = (ksl & 1) * 32;
            u32 vplo = half ? vzp : vzo;        // global h pairs 0..63
            u32 vphi = half ? vzo : vzp;        // global h pairs 64..127
            float p0 = 0.f, p1 = 0.f;
#pragma unroll
            for (int k = 0; k < 32; k += 2) {
                u32 h0b = (ksl < 2) ? rl(vplo, kb + k)     : rl(vphi, kb + k);
                u32 h1b = (ksl < 2) ? rl(vplo, kb + k + 1) : rl(vphi, kb + k + 1);
                p0 = dot2acc(h0b, s_ow[(k)     * 256 + t], p0);
                p1 = dot2acc(h1b, s_ow[(k + 1) * 256 + t], p1);
            }
            s_op[s & 1][(t & 63) * 4 + ksl] = p0 + p1;
        }
        if (s >= 2 && lane >= 32 && lane < 48) {   // store decoded[s-2]
            int r = w * 16 + (lane - 32);
            const float* sp = s_op[(s - 1) & 1];
            float y = outb_r + ((sp[r*4+0] + sp[r*4+1]) + (sp[r*4+2] + sp[r*4+3]));
            out[((size_t)b * Ts + (s - 2)) * Ic + half * 64 + r] = y;
        }
        block_sync_lds();
    }

    // tail 1: pending decoded[Ts-2]
    if (lane >= 32 && lane < 48) {
        int r = w * 16 + (lane - 32);
        const float* sp = s_op[(Ts - 1) & 1];
        float y = outb_r + ((sp[r*4+0] + sp[r*4+1]) + (sp[r*4+2] + sp[r*4+3]));
        out[((size_t)b * Ts + (Ts - 2)) * Ic + half * 64 + r] = y;
    }
    // tail 2: decoded[Ts-1] from h_Ts
    {
        u32 vzo2 = s_zh[Ts & 1][lane];
        const u64* pslot = &xch_peer[(Ts & 1) * 64 + lane];
        u64 pv = aload64(pslot);
        while ((u32)(pv >> 32) < (u32)Ts) {
            __builtin_amdgcn_s_sleep(1);
            pv = aload64(pslot);
        }
        u32 vzp2 = (u32)pv;
        const int ksl = t >> 6;
        const int kb  = (ksl & 1) * 32;
        u32 vplo = half ? vzp2 : vzo2;
        u32 vphi = half ? vzo2 : vzp2;
        float p0 = 0.f, p1 = 0.f;
#pragma unroll
        for (int k = 0; k < 32; k += 2) {
            u32 h0b = (ksl < 2) ? rl(vplo, kb + k)     : rl(vphi, kb + k);
            u32 h1b = (ksl < 2) ? rl(vplo, kb + k + 1) : rl(vphi, kb + k + 1);
            p0 = dot2acc(h0b, s_ow[(k)     * 256 + t], p0);
            p1 = dot2acc(h1b, s_ow[(k + 1) * 256 + t], p1);
        }
        s_op[Ts & 1][(t & 63) * 4 + ksl] = p0 + p1;
    }
    block_sync_lds();
    if (lane >= 32 && lane < 48) {
        int r = w * 16 + (lane - 32);
        const float* sp = s_op[Ts & 1];
        float y = outb_r + ((sp[r*4+0] + sp[r*4+1]) + (sp[r*4+2] + sp[r*4+3]));
        out[((size_t)b * Ts + (Ts - 1)) * Ic + half * 64 + r] = y;
    }
}

extern "C" void kernel_launch(void* const* d_in, const int* in_sizes, int n_in,
                              void* d_out, int out_size, void* d_ws, size_t ws_size,
                              hipStream_t stream)
{
    const float* x    = (const float*)d_in[0];
    const float* WihF = (const float*)d_in[1];
    const float* WhhF = (const float*)d_in[2];
    const float* bihF = (const float*)d_in[3];
    const float* bhhF = (const float*)d_in[4];
    const float* WihB = (const float*)d_in[5];
    const float* WhhB = (const float*)d_in[6];
    const float* bihB = (const float*)d_in[7];
    const float* bhhB = (const float*)d_in[8];
    const float* latW = (const float*)d_in[9];
    const float* latb = (const float*)d_in[10];
    const float* l2hW = (const float*)d_in[11];
    const float* l2hb = (const float*)d_in[12];
    const float* dWih = (const float*)d_in[13];
    const float* dWhh = (const float*)d_in[14];
    const float* dbih = (const float*)d_in[15];
    const float* dbhh = (const float*)d_in[16];
    const float* outW = (const float*)d_in[17];
    const float* outb = (const float*)d_in[18];

    const int T = in_sizes[0] / (64 * Ic);  // 4096

    float* ws  = (float*)d_ws;
    float* hFp = ws;                 // [64,256]
    float* hBp = ws + 16384;         // [64,256]
    float* hid = ws + 32768;         // [64,256]
    u64* encXch = (u64*)(ws + 49152);   // 128*2*2*64 = 32768 u64
    u64* decXch = encXch + 32768;       // 64*2*2*64  = 16384 u64

    // zero all tags (graph replay must restart deterministically)
    hipMemsetAsync(encXch, 0, (32768 + 16384) * sizeof(u64), stream);

    enc_kernel<<<256, 256, 0, stream>>>(x, WihF, WhhF, bihF, bhhF,
                                        WihB, WhhB, bihB, bhhB,
                                        hFp, hBp, encXch, T);
    lat_kernel<<<64, 256, 0, stream>>>(hFp, hBp, latW, latb, l2hW, l2hb, hid);
    dec_kernel<<<128, 256, 0, stream>>>(x, dWih, dWhh, dbih, dbhh,
                                        outW, outb, hid, (float*)d_out,
                                        decXch, T);
}